// Round 1
// baseline (666.625 us; speedup 1.0000x reference)
//
#include <hip/hip_runtime.h>

#define N_NODES 50000
#define N_EDGES 800000
#define D 128

// ---------------- degree / norm ----------------
__global__ void k_degrees(const int* __restrict__ src, const int* __restrict__ dst,
                          int* __restrict__ outdeg, int* __restrict__ indeg) {
    int e = blockIdx.x * blockDim.x + threadIdx.x;
    if (e < N_EDGES) {
        atomicAdd(&outdeg[src[e]], 1);
        atomicAdd(&indeg[dst[e]], 1);
    }
}

__global__ void k_norm(const int* __restrict__ outdeg, float* __restrict__ norm) {
    int i = blockIdx.x * blockDim.x + threadIdx.x;
    if (i < N_NODES) {
        float d = (float)outdeg[i];
        norm[i] = 1.0f / sqrtf(fmaxf(d, 1.0f));
    }
}

// ---------------- exclusive scan of in-degree -> CSR offsets ----------------
__global__ void k_scan(const int* __restrict__ indeg, int* __restrict__ off) {
    __shared__ int part[1024];
    int t = threadIdx.x;
    const int chunk = (N_NODES + 1023) / 1024;
    int b = t * chunk;
    int e = b + chunk; if (e > N_NODES) e = N_NODES;
    if (b > N_NODES) b = N_NODES;
    int s = 0;
    for (int i = b; i < e; ++i) s += indeg[i];
    part[t] = s;
    __syncthreads();
    // inclusive Hillis-Steele scan
    for (int d = 1; d < 1024; d <<= 1) {
        int v = part[t];
        int o = (t >= d) ? part[t - d] : 0;
        __syncthreads();
        part[t] = v + o;
        __syncthreads();
    }
    int run = part[t] - s;  // exclusive base for this chunk
    for (int i = b; i < e; ++i) { off[i] = run; run += indeg[i]; }
    if (t == 1023) off[N_NODES] = part[1023];
}

__global__ void k_fill(const int* __restrict__ src, const int* __restrict__ dst,
                       const int* __restrict__ off, int* __restrict__ cnt,
                       int* __restrict__ csrc) {
    int e = blockIdx.x * blockDim.x + threadIdx.x;
    if (e < N_EDGES) {
        int d = dst[e];
        int p = atomicAdd(&cnt[d], 1);
        csrc[off[d] + p] = src[e];
    }
}

// ---------------- per-layer init: sum = X, A = X * norm ----------------
__global__ void k_init(const float* __restrict__ X, const float* __restrict__ norm,
                       float* __restrict__ sum, float* __restrict__ A) {
    int i = blockIdx.x * blockDim.x + threadIdx.x;  // float4 index
    const int total = N_NODES * (D / 4);
    if (i < total) {
        int row = i >> 5;
        float4 v = ((const float4*)X)[i];
        ((float4*)sum)[i] = v;
        float nm = norm[row];
        float4 a = {v.x * nm, v.y * nm, v.z * nm, v.w * nm};
        ((float4*)A)[i] = a;
    }
}

// ---------------- propagation hop: one wave per node ----------------
// acc = sum_{e: dst==node} Ain[src[e]]; X = acc*norm; sum += X; Bout = X*norm
__global__ __launch_bounds__(256) void k_prop(const float* __restrict__ Ain,
                       const int* __restrict__ off, const int* __restrict__ csrc,
                       const float* __restrict__ norm,
                       float* __restrict__ sum, float* __restrict__ Bout) {
    int w = blockIdx.x * 4 + (threadIdx.x >> 6);
    int lane = threadIdx.x & 63;
    if (w >= N_NODES) return;
    int s0 = off[w], s1 = off[w + 1];
    float ax = 0.f, ay = 0.f;
    const float2* A2 = (const float2*)Ain;
    for (int j = s0; j < s1; ++j) {
        int s = csrc[j];
        float2 v = A2[(size_t)s * 64 + lane];
        ax += v.x; ay += v.y;
    }
    float nm = norm[w];
    float x = ax * nm, y = ay * nm;
    size_t idx = (size_t)w * 64 + lane;
    float2 sv = ((float2*)sum)[idx];
    sv.x += x; sv.y += y;
    ((float2*)sum)[idx] = sv;
    float2 bv = {x * nm, y * nm};
    ((float2*)Bout)[idx] = bv;
}

// ---------------- out = relu(A @ W + bscale*bias), A:[M,128] W:[128,128] ----------------
__global__ __launch_bounds__(256) void k_gemm_relu(const float* __restrict__ A,
        const float* __restrict__ W, const float* __restrict__ bias,
        float* __restrict__ out, float bscale) {
    __shared__ float Ws[128 * 128];   // 64 KB
    __shared__ float As[64 * 128];    // 32 KB
    int t = threadIdx.x;
    int row0 = blockIdx.x * 64;
    const float4* W4 = (const float4*)W;
    float4* Ws4 = (float4*)Ws;
#pragma unroll
    for (int i = 0; i < 16; ++i) Ws4[t + i * 256] = W4[t + i * 256];
    float4* As4 = (float4*)As;
    for (int i = t; i < 64 * 32; i += 256) {
        int r = row0 + (i >> 5);
        float4 v = {0.f, 0.f, 0.f, 0.f};
        if (r < N_NODES) v = ((const float4*)A)[(size_t)r * 32 + (i & 31)];
        As4[i] = v;
    }
    __syncthreads();
    int r0 = (t >> 5) * 8;     // 8 rows per thread
    int c4 = t & 31;           // float4 column group (4 cols)
    float acc[8][4] = {};
#pragma unroll 4
    for (int k = 0; k < 128; ++k) {
        float4 wv = ((float4*)Ws)[k * 32 + c4];
#pragma unroll
        for (int i = 0; i < 8; ++i) {
            float a = As[(r0 + i) * 128 + k];
            acc[i][0] += a * wv.x;
            acc[i][1] += a * wv.y;
            acc[i][2] += a * wv.z;
            acc[i][3] += a * wv.w;
        }
    }
    float4 bv = ((const float4*)bias)[c4];
    bv.x *= bscale; bv.y *= bscale; bv.z *= bscale; bv.w *= bscale;
#pragma unroll
    for (int i = 0; i < 8; ++i) {
        int r = row0 + r0 + i;
        if (r < N_NODES) {
            float4 o;
            o.x = fmaxf(acc[i][0] + bv.x, 0.f);
            o.y = fmaxf(acc[i][1] + bv.y, 0.f);
            o.z = fmaxf(acc[i][2] + bv.z, 0.f);
            o.w = fmaxf(acc[i][3] + bv.w, 0.f);
            ((float4*)out)[(size_t)r * 32 + c4] = o;
        }
    }
}

extern "C" void kernel_launch(void* const* d_in, const int* in_sizes, int n_in,
                              void* d_out, int out_size, void* d_ws, size_t ws_size,
                              hipStream_t stream) {
    const float* feat = (const float*)d_in[0];
    const float* W1   = (const float*)d_in[1];
    const float* b1   = (const float*)d_in[2];
    const float* W2   = (const float*)d_in[3];
    const float* b2   = (const float*)d_in[4];
    const int*   src  = (const int*)d_in[5];
    const int*   dst  = (const int*)d_in[6];
    float* out = (float*)d_out;

    char* ws = (char*)d_ws;
    size_t o = 0;
    auto alloc = [&](size_t bytes) {
        void* p = ws + o;
        o += (bytes + 1023) & ~(size_t)1023;
        return p;
    };
    int*   outdeg = (int*)alloc(N_NODES * 4);
    int*   indeg  = (int*)alloc(N_NODES * 4);
    int*   cnt    = (int*)alloc(N_NODES * 4);
    float* norm   = (float*)alloc(N_NODES * 4);
    int*   off    = (int*)alloc((N_NODES + 1) * 4);
    int*   csrc   = (int*)alloc((size_t)N_EDGES * 4);
    float* bufA   = (float*)alloc((size_t)N_NODES * D * 4);
    float* bufB   = (float*)alloc((size_t)N_NODES * D * 4);
    float* sum    = (float*)alloc((size_t)N_NODES * D * 4);
    (void)ws_size; (void)in_sizes; (void)n_in; (void)out_size;

    hipMemsetAsync(outdeg, 0, N_NODES * 4, stream);
    hipMemsetAsync(indeg, 0, N_NODES * 4, stream);
    hipMemsetAsync(cnt, 0, N_NODES * 4, stream);

    k_degrees<<<(N_EDGES + 255) / 256, 256, 0, stream>>>(src, dst, outdeg, indeg);
    k_norm<<<(N_NODES + 255) / 256, 256, 0, stream>>>(outdeg, norm);
    k_scan<<<1, 1024, 0, stream>>>(indeg, off);
    k_fill<<<(N_EDGES + 255) / 256, 256, 0, stream>>>(src, dst, off, cnt, csrc);

    const int f4total = N_NODES * 32;
    const int init_blocks = (f4total + 255) / 256;
    const int prop_blocks = (N_NODES + 3) / 4;
    const int gemm_blocks = (N_NODES + 63) / 64;

    // ---- layer 1: input feat -> h (stored in d_out) ----
    k_init<<<init_blocks, 256, 0, stream>>>(feat, norm, sum, bufA);
    k_prop<<<prop_blocks, 256, 0, stream>>>(bufA, off, csrc, norm, sum, bufB);
    k_prop<<<prop_blocks, 256, 0, stream>>>(bufB, off, csrc, norm, sum, bufA);
    k_gemm_relu<<<gemm_blocks, 256, 0, stream>>>(sum, W1, b1, out, 3.0f);

    // ---- layer 2: input h (d_out) -> d_out ----
    k_init<<<init_blocks, 256, 0, stream>>>(out, norm, sum, bufA);
    k_prop<<<prop_blocks, 256, 0, stream>>>(bufA, off, csrc, norm, sum, bufB);
    k_prop<<<prop_blocks, 256, 0, stream>>>(bufB, off, csrc, norm, sum, bufA);
    k_gemm_relu<<<gemm_blocks, 256, 0, stream>>>(sum, W2, b2, out, 3.0f);
}

// Round 2
// 529.704 us; speedup vs baseline: 1.2585x; 1.2585x over previous
//
#include <hip/hip_runtime.h>

#define N_NODES 50000
#define N_EDGES 800000
#define D 128

// ---------------- degree / norm ----------------
__global__ void k_degrees(const int* __restrict__ src, const int* __restrict__ dst,
                          int* __restrict__ outdeg, int* __restrict__ indeg) {
    int e = blockIdx.x * blockDim.x + threadIdx.x;
    if (e < N_EDGES) {
        atomicAdd(&outdeg[src[e]], 1);
        atomicAdd(&indeg[dst[e]], 1);
    }
}

__global__ void k_norm(const int* __restrict__ outdeg, float* __restrict__ norm) {
    int i = blockIdx.x * blockDim.x + threadIdx.x;
    if (i < N_NODES) {
        float d = (float)outdeg[i];
        norm[i] = 1.0f / sqrtf(fmaxf(d, 1.0f));
    }
}

// ---------------- exclusive scan of in-degree -> CSR offsets ----------------
__global__ void k_scan(const int* __restrict__ indeg, int* __restrict__ off) {
    __shared__ int part[1024];
    int t = threadIdx.x;
    const int chunk = (N_NODES + 1023) / 1024;
    int b = t * chunk;
    int e = b + chunk; if (e > N_NODES) e = N_NODES;
    if (b > N_NODES) b = N_NODES;
    int s = 0;
    for (int i = b; i < e; ++i) s += indeg[i];
    part[t] = s;
    __syncthreads();
    for (int d = 1; d < 1024; d <<= 1) {
        int v = part[t];
        int o = (t >= d) ? part[t - d] : 0;
        __syncthreads();
        part[t] = v + o;
        __syncthreads();
    }
    int run = part[t] - s;
    for (int i = b; i < e; ++i) { off[i] = run; run += indeg[i]; }
    if (t == 1023) off[N_NODES] = part[1023];
}

__global__ void k_fill(const int* __restrict__ src, const int* __restrict__ dst,
                       const int* __restrict__ off, int* __restrict__ cnt,
                       int* __restrict__ csrc) {
    int e = blockIdx.x * blockDim.x + threadIdx.x;
    if (e < N_EDGES) {
        int d = dst[e];
        int p = atomicAdd(&cnt[d], 1);
        csrc[off[d] + p] = src[e];
    }
}

// ---------------- layer-1 init: A = X * norm ----------------
__global__ void k_init(const float* __restrict__ X, const float* __restrict__ norm,
                       float* __restrict__ A) {
    int i = blockIdx.x * blockDim.x + threadIdx.x;  // float4 index
    const int total = N_NODES * (D / 4);
    if (i < total) {
        int row = i >> 5;
        float4 v = ((const float4*)X)[i];
        float nm = norm[row];
        float4 a = {v.x * nm, v.y * nm, v.z * nm, v.w * nm};
        ((float4*)A)[i] = a;
    }
}

// ---------------- propagation hop: one wave per node, 8-wide MLP ----------------
// X = (sum_{e: dst==node} Ain[src[e]]) * norm[node]
// accum ? Xsum += X : Xsum = X;   if (Anext) Anext = X * norm
__global__ __launch_bounds__(256) void k_prop(const float* __restrict__ Ain,
                       const int* __restrict__ off, const int* __restrict__ csrc,
                       const float* __restrict__ norm,
                       float* __restrict__ Xsum, float* __restrict__ Anext,
                       int accum) {
    int w = blockIdx.x * 4 + (threadIdx.x >> 6);
    if (w >= N_NODES) return;
    int lane = threadIdx.x & 63;
    int s0 = off[w], s1 = off[w + 1];
    float ax = 0.f, ay = 0.f;
    const float2* A2 = (const float2*)Ain;
    if (s1 > s0) {
        int j = s0;
        int jend = s0 + ((s1 - s0) & ~7);
        for (; j < jend; j += 8) {
            int i0 = csrc[j + 0], i1 = csrc[j + 1], i2 = csrc[j + 2], i3 = csrc[j + 3];
            int i4 = csrc[j + 4], i5 = csrc[j + 5], i6 = csrc[j + 6], i7 = csrc[j + 7];
            float2 v0 = A2[(size_t)i0 * 64 + lane];
            float2 v1 = A2[(size_t)i1 * 64 + lane];
            float2 v2 = A2[(size_t)i2 * 64 + lane];
            float2 v3 = A2[(size_t)i3 * 64 + lane];
            float2 v4 = A2[(size_t)i4 * 64 + lane];
            float2 v5 = A2[(size_t)i5 * 64 + lane];
            float2 v6 = A2[(size_t)i6 * 64 + lane];
            float2 v7 = A2[(size_t)i7 * 64 + lane];
            ax += ((v0.x + v1.x) + (v2.x + v3.x)) + ((v4.x + v5.x) + (v6.x + v7.x));
            ay += ((v0.y + v1.y) + (v2.y + v3.y)) + ((v4.y + v5.y) + (v6.y + v7.y));
        }
        if (j < s1) {
#pragma unroll
            for (int k = 0; k < 8; ++k) {
                int jj = j + k;
                int jc = jj < s1 ? jj : s1 - 1;
                int s = csrc[jc];
                float2 v = A2[(size_t)s * 64 + lane];
                if (jj < s1) { ax += v.x; ay += v.y; }
            }
        }
    }
    float nm = norm[w];
    float x = ax * nm, y = ay * nm;
    size_t idx = (size_t)w * 64 + lane;
    if (accum) {
        float2 sv = ((float2*)Xsum)[idx];
        float2 o = {sv.x + x, sv.y + y};
        ((float2*)Xsum)[idx] = o;
    } else {
        float2 o = {x, y};
        ((float2*)Xsum)[idx] = o;
    }
    if (Anext) {
        float2 b = {x * nm, y * nm};
        ((float2*)Anext)[idx] = b;
    }
}

// ---------------- out = relu((X0+Xsum) @ W + bscale*bias); opt Anext = out*norm ----
__global__ __launch_bounds__(256) void k_gemm_relu(const float* __restrict__ X0,
        const float* __restrict__ Xsum,
        const float* __restrict__ W, const float* __restrict__ bias,
        float* __restrict__ out, float* __restrict__ Anext,
        const float* __restrict__ norm, float bscale) {
    __shared__ float As[32 * 128];   // 16 KB
    int t = threadIdx.x;
    int row0 = blockIdx.x * 32;
    float4* As4 = (float4*)As;
    for (int i = t; i < 32 * 32; i += 256) {
        int r = row0 + (i >> 5);
        float4 v = {0.f, 0.f, 0.f, 0.f};
        if (r < N_NODES) {
            float4 a = ((const float4*)X0)[(size_t)r * 32 + (i & 31)];
            float4 b = ((const float4*)Xsum)[(size_t)r * 32 + (i & 31)];
            v.x = a.x + b.x; v.y = a.y + b.y; v.z = a.z + b.z; v.w = a.w + b.w;
        }
        As4[i] = v;
    }
    __syncthreads();
    int r0 = (t >> 5) * 4;     // 4 rows per thread
    int c4 = t & 31;           // float4 column group
    float acc[4][4] = {};
    const float4* W4 = (const float4*)W;
#pragma unroll 2
    for (int k4 = 0; k4 < 32; ++k4) {
        float4 wv[4];
#pragma unroll
        for (int kk = 0; kk < 4; ++kk) wv[kk] = W4[(size_t)(k4 * 4 + kk) * 32 + c4];
        float4 av[4];
#pragma unroll
        for (int i = 0; i < 4; ++i) av[i] = As4[(r0 + i) * 32 + k4];
#pragma unroll
        for (int i = 0; i < 4; ++i) {
            acc[i][0] += av[i].x * wv[0].x + av[i].y * wv[1].x + av[i].z * wv[2].x + av[i].w * wv[3].x;
            acc[i][1] += av[i].x * wv[0].y + av[i].y * wv[1].y + av[i].z * wv[2].y + av[i].w * wv[3].y;
            acc[i][2] += av[i].x * wv[0].z + av[i].y * wv[1].z + av[i].z * wv[2].z + av[i].w * wv[3].z;
            acc[i][3] += av[i].x * wv[0].w + av[i].y * wv[1].w + av[i].z * wv[2].w + av[i].w * wv[3].w;
        }
    }
    float4 bv = ((const float4*)bias)[c4];
    bv.x *= bscale; bv.y *= bscale; bv.z *= bscale; bv.w *= bscale;
#pragma unroll
    for (int i = 0; i < 4; ++i) {
        int r = row0 + r0 + i;
        if (r < N_NODES) {
            float4 o;
            o.x = fmaxf(acc[i][0] + bv.x, 0.f);
            o.y = fmaxf(acc[i][1] + bv.y, 0.f);
            o.z = fmaxf(acc[i][2] + bv.z, 0.f);
            o.w = fmaxf(acc[i][3] + bv.w, 0.f);
            ((float4*)out)[(size_t)r * 32 + c4] = o;
            if (Anext) {
                float nm = norm[r];
                float4 a = {o.x * nm, o.y * nm, o.z * nm, o.w * nm};
                ((float4*)Anext)[(size_t)r * 32 + c4] = a;
            }
        }
    }
}

extern "C" void kernel_launch(void* const* d_in, const int* in_sizes, int n_in,
                              void* d_out, int out_size, void* d_ws, size_t ws_size,
                              hipStream_t stream) {
    const float* feat = (const float*)d_in[0];
    const float* W1   = (const float*)d_in[1];
    const float* b1   = (const float*)d_in[2];
    const float* W2   = (const float*)d_in[3];
    const float* b2   = (const float*)d_in[4];
    const int*   src  = (const int*)d_in[5];
    const int*   dst  = (const int*)d_in[6];
    float* out = (float*)d_out;

    char* ws = (char*)d_ws;
    size_t o = 0;
    auto alloc = [&](size_t bytes) {
        void* p = ws + o;
        o += (bytes + 1023) & ~(size_t)1023;
        return p;
    };
    int*   outdeg = (int*)alloc(N_NODES * 4);      // these three contiguous:
    int*   indeg  = (int*)alloc(N_NODES * 4);      //   one memset covers them
    int*   cnt    = (int*)alloc(N_NODES * 4);
    float* norm   = (float*)alloc(N_NODES * 4);
    int*   off    = (int*)alloc((N_NODES + 1) * 4);
    int*   csrc   = (int*)alloc((size_t)N_EDGES * 4);
    float* bufA   = (float*)alloc((size_t)N_NODES * D * 4);
    float* bufB   = (float*)alloc((size_t)N_NODES * D * 4);
    float* Xsum   = (float*)alloc((size_t)N_NODES * D * 4);
    (void)ws_size; (void)in_sizes; (void)n_in; (void)out_size;

    const size_t pad = ((size_t)N_NODES * 4 + 1023) & ~(size_t)1023;
    hipMemsetAsync(outdeg, 0, pad * 3, stream);

    k_degrees<<<(N_EDGES + 255) / 256, 256, 0, stream>>>(src, dst, outdeg, indeg);
    k_norm<<<(N_NODES + 255) / 256, 256, 0, stream>>>(outdeg, norm);
    k_scan<<<1, 1024, 0, stream>>>(indeg, off);
    k_fill<<<(N_EDGES + 255) / 256, 256, 0, stream>>>(src, dst, off, cnt, csrc);

    const int init_blocks = (N_NODES * 32 + 255) / 256;
    const int prop_blocks = (N_NODES + 3) / 4;
    const int gemm_blocks = (N_NODES + 31) / 32;

    // ---- layer 1 ----
    k_init<<<init_blocks, 256, 0, stream>>>(feat, norm, bufA);
    k_prop<<<prop_blocks, 256, 0, stream>>>(bufA, off, csrc, norm, Xsum, bufB, 0);
    k_prop<<<prop_blocks, 256, 0, stream>>>(bufB, off, csrc, norm, Xsum, nullptr, 1);
    // out = relu((feat + Xsum)W1 + 3b1); bufA = out*norm (layer-2 gather input)
    k_gemm_relu<<<gemm_blocks, 256, 0, stream>>>(feat, Xsum, W1, b1, out, bufA, norm, 3.0f);

    // ---- layer 2 ----
    k_prop<<<prop_blocks, 256, 0, stream>>>(bufA, off, csrc, norm, Xsum, bufB, 0);
    k_prop<<<prop_blocks, 256, 0, stream>>>(bufB, off, csrc, norm, Xsum, nullptr, 1);
    k_gemm_relu<<<gemm_blocks, 256, 0, stream>>>(out, Xsum, W2, b2, out, nullptr, norm, 3.0f);
}

// Round 3
// 469.402 us; speedup vs baseline: 1.4202x; 1.1285x over previous
//
#include <hip/hip_runtime.h>

#define N_NODES 50000
#define N_EDGES 800000
#define D 128
#define NSB ((N_NODES + 255) / 256)   // 196 scan blocks

// ---------------- degree / norm ----------------
__global__ void k_degrees(const int* __restrict__ src, const int* __restrict__ dst,
                          int* __restrict__ outdeg, int* __restrict__ indeg) {
    int e = blockIdx.x * blockDim.x + threadIdx.x;
    if (e < N_EDGES) {
        atomicAdd(&outdeg[src[e]], 1);
        atomicAdd(&indeg[dst[e]], 1);
    }
}

__global__ void k_norm(const int* __restrict__ outdeg, float* __restrict__ norm) {
    int i = blockIdx.x * blockDim.x + threadIdx.x;
    if (i < N_NODES) {
        float d = (float)outdeg[i];
        norm[i] = 1.0f / sqrtf(fmaxf(d, 1.0f));
    }
}

// ---------------- two-level exclusive scan of in-degree -> CSR offsets ----------------
__global__ void k_scanA(const int* __restrict__ indeg, int* __restrict__ off,
                        int* __restrict__ bsum) {
    __shared__ int sh[256];
    int t = threadIdx.x;
    int i = blockIdx.x * 256 + t;
    int v = (i < N_NODES) ? indeg[i] : 0;
    sh[t] = v;
    __syncthreads();
    for (int d = 1; d < 256; d <<= 1) {
        int x = sh[t];
        int y = (t >= d) ? sh[t - d] : 0;
        __syncthreads();
        sh[t] = x + y;
        __syncthreads();
    }
    if (i < N_NODES) off[i] = sh[t] - v;          // exclusive within block
    if (t == 255) bsum[blockIdx.x] = sh[255];
}

__global__ void k_scanB(const int* __restrict__ bsum, int* __restrict__ bbase,
                        int* __restrict__ off) {
    __shared__ int sh[256];
    int t = threadIdx.x;
    int v = (t < NSB) ? bsum[t] : 0;
    sh[t] = v;
    __syncthreads();
    for (int d = 1; d < 256; d <<= 1) {
        int x = sh[t];
        int y = (t >= d) ? sh[t - d] : 0;
        __syncthreads();
        sh[t] = x + y;
        __syncthreads();
    }
    if (t < NSB) bbase[t] = sh[t] - v;            // exclusive block base
    if (t == 255) off[N_NODES] = sh[255];
}

__global__ void k_scanC(int* __restrict__ off, const int* __restrict__ bbase) {
    int t = threadIdx.x;
    int i = blockIdx.x * 256 + t;
    if (i < N_NODES) off[i] += bbase[blockIdx.x];
}

__global__ void k_fill(const int* __restrict__ src, const int* __restrict__ dst,
                       const int* __restrict__ off, int* __restrict__ cnt,
                       int* __restrict__ csrc) {
    int e = blockIdx.x * blockDim.x + threadIdx.x;
    if (e < N_EDGES) {
        int d = dst[e];
        int p = atomicAdd(&cnt[d], 1);
        csrc[off[d] + p] = src[e];
    }
}

// ---------------- layer-1 init: A = X * norm ----------------
__global__ void k_init(const float* __restrict__ X, const float* __restrict__ norm,
                       float* __restrict__ A) {
    int i = blockIdx.x * blockDim.x + threadIdx.x;  // float4 index
    const int total = N_NODES * (D / 4);
    if (i < total) {
        int row = i >> 5;
        float4 v = ((const float4*)X)[i];
        float nm = norm[row];
        float4 a = {v.x * nm, v.y * nm, v.z * nm, v.w * nm};
        ((float4*)A)[i] = a;
    }
}

// ---------------- propagation hop: one wave per node, paired-float4 gathers ----
// X = (sum_{e: dst==node} Ain[src[e]]) * norm[node]
// accum ? Xsum += X : Xsum = X;   if (Anext) Anext = X * norm
__global__ __launch_bounds__(256) void k_prop(const float* __restrict__ Ain,
                       const int* __restrict__ off, const int* __restrict__ csrc,
                       const float* __restrict__ norm,
                       float* __restrict__ Xsum, float* __restrict__ Anext,
                       int accum) {
    int w = blockIdx.x * 4 + (threadIdx.x >> 6);
    if (w >= N_NODES) return;
    int lane = threadIdx.x & 63;
    int half = lane >> 5;          // lanes 0-31 do even edges, 32-63 odd edges
    int c4 = lane & 31;            // float4 column group within the row
    int s0 = off[w], s1 = off[w + 1];
    float4 acc = {0.f, 0.f, 0.f, 0.f};
    const float4* A4 = (const float4*)Ain;
    // 16 edges per iteration: 8 paired 1KB gather instructions in flight
    for (int j = s0; j < s1; j += 16) {
#pragma unroll
        for (int k = 0; k < 8; ++k) {
            int jj = j + 2 * k + half;
            int jc = jj < s1 ? jj : s0;          // clamp (valid: loop implies s1>s0)
            int s = csrc[jc];
            float4 v = A4[(size_t)s * 32 + c4];
            if (jj < s1) {
                acc.x += v.x; acc.y += v.y; acc.z += v.z; acc.w += v.w;
            }
        }
    }
    // combine the two half-wave partial sums
    acc.x += __shfl_xor(acc.x, 32);
    acc.y += __shfl_xor(acc.y, 32);
    acc.z += __shfl_xor(acc.z, 32);
    acc.w += __shfl_xor(acc.w, 32);
    float nm = norm[w];
    float4 X = {acc.x * nm, acc.y * nm, acc.z * nm, acc.w * nm};
    size_t base = (size_t)w * 32 + c4;
    if (half == 0) {
        float4 o = X;
        if (accum) {
            float4 sv = ((float4*)Xsum)[base];
            o.x += sv.x; o.y += sv.y; o.z += sv.z; o.w += sv.w;
        }
        ((float4*)Xsum)[base] = o;
    } else if (Anext) {
        float4 b = {X.x * nm, X.y * nm, X.z * nm, X.w * nm};
        ((float4*)Anext)[base] = b;
    }
}

// ---------------- out = relu((X0+Xsum) @ W + bscale*bias); opt Anext = out*norm ----
__global__ __launch_bounds__(256) void k_gemm_relu(const float* __restrict__ X0,
        const float* __restrict__ Xsum,
        const float* __restrict__ W, const float* __restrict__ bias,
        float* __restrict__ out, float* __restrict__ Anext,
        const float* __restrict__ norm, float bscale) {
    __shared__ float As[32 * 128];   // 16 KB
    int t = threadIdx.x;
    int row0 = blockIdx.x * 32;
    float4* As4 = (float4*)As;
    for (int i = t; i < 32 * 32; i += 256) {
        int r = row0 + (i >> 5);
        float4 v = {0.f, 0.f, 0.f, 0.f};
        if (r < N_NODES) {
            float4 a = ((const float4*)X0)[(size_t)r * 32 + (i & 31)];
            float4 b = ((const float4*)Xsum)[(size_t)r * 32 + (i & 31)];
            v.x = a.x + b.x; v.y = a.y + b.y; v.z = a.z + b.z; v.w = a.w + b.w;
        }
        As4[i] = v;
    }
    __syncthreads();
    int r0 = (t >> 5) * 4;     // 4 rows per thread
    int c4 = t & 31;           // float4 column group
    float acc[4][4] = {};
    const float4* W4 = (const float4*)W;
#pragma unroll 2
    for (int k4 = 0; k4 < 32; ++k4) {
        float4 wv[4];
#pragma unroll
        for (int kk = 0; kk < 4; ++kk) wv[kk] = W4[(size_t)(k4 * 4 + kk) * 32 + c4];
        float4 av[4];
#pragma unroll
        for (int i = 0; i < 4; ++i) av[i] = As4[(r0 + i) * 32 + k4];
#pragma unroll
        for (int i = 0; i < 4; ++i) {
            acc[i][0] += av[i].x * wv[0].x + av[i].y * wv[1].x + av[i].z * wv[2].x + av[i].w * wv[3].x;
            acc[i][1] += av[i].x * wv[0].y + av[i].y * wv[1].y + av[i].z * wv[2].y + av[i].w * wv[3].y;
            acc[i][2] += av[i].x * wv[0].z + av[i].y * wv[1].z + av[i].z * wv[2].z + av[i].w * wv[3].z;
            acc[i][3] += av[i].x * wv[0].w + av[i].y * wv[1].w + av[i].z * wv[2].w + av[i].w * wv[3].w;
        }
    }
    float4 bv = ((const float4*)bias)[c4];
    bv.x *= bscale; bv.y *= bscale; bv.z *= bscale; bv.w *= bscale;
#pragma unroll
    for (int i = 0; i < 4; ++i) {
        int r = row0 + r0 + i;
        if (r < N_NODES) {
            float4 o;
            o.x = fmaxf(acc[i][0] + bv.x, 0.f);
            o.y = fmaxf(acc[i][1] + bv.y, 0.f);
            o.z = fmaxf(acc[i][2] + bv.z, 0.f);
            o.w = fmaxf(acc[i][3] + bv.w, 0.f);
            ((float4*)out)[(size_t)r * 32 + c4] = o;
            if (Anext) {
                float nm = norm[r];
                float4 a = {o.x * nm, o.y * nm, o.z * nm, o.w * nm};
                ((float4*)Anext)[(size_t)r * 32 + c4] = a;
            }
        }
    }
}

extern "C" void kernel_launch(void* const* d_in, const int* in_sizes, int n_in,
                              void* d_out, int out_size, void* d_ws, size_t ws_size,
                              hipStream_t stream) {
    const float* feat = (const float*)d_in[0];
    const float* W1   = (const float*)d_in[1];
    const float* b1   = (const float*)d_in[2];
    const float* W2   = (const float*)d_in[3];
    const float* b2   = (const float*)d_in[4];
    const int*   src  = (const int*)d_in[5];
    const int*   dst  = (const int*)d_in[6];
    float* out = (float*)d_out;

    char* ws = (char*)d_ws;
    size_t o = 0;
    auto alloc = [&](size_t bytes) {
        void* p = ws + o;
        o += (bytes + 1023) & ~(size_t)1023;
        return p;
    };
    int*   outdeg = (int*)alloc(N_NODES * 4);      // these three contiguous:
    int*   indeg  = (int*)alloc(N_NODES * 4);      //   one memset covers them
    int*   cnt    = (int*)alloc(N_NODES * 4);
    float* norm   = (float*)alloc(N_NODES * 4);
    int*   off    = (int*)alloc((N_NODES + 1) * 4);
    int*   bsum   = (int*)alloc(NSB * 4);
    int*   bbase  = (int*)alloc(NSB * 4);
    int*   csrc   = (int*)alloc((size_t)N_EDGES * 4);
    float* bufA   = (float*)alloc((size_t)N_NODES * D * 4);
    float* bufB   = (float*)alloc((size_t)N_NODES * D * 4);
    float* Xsum   = (float*)alloc((size_t)N_NODES * D * 4);
    (void)ws_size; (void)in_sizes; (void)n_in; (void)out_size;

    const size_t pad = ((size_t)N_NODES * 4 + 1023) & ~(size_t)1023;
    hipMemsetAsync(outdeg, 0, pad * 3, stream);

    k_degrees<<<(N_EDGES + 255) / 256, 256, 0, stream>>>(src, dst, outdeg, indeg);
    k_norm<<<(N_NODES + 255) / 256, 256, 0, stream>>>(outdeg, norm);
    k_scanA<<<NSB, 256, 0, stream>>>(indeg, off, bsum);
    k_scanB<<<1, 256, 0, stream>>>(bsum, bbase, off);
    k_scanC<<<NSB, 256, 0, stream>>>(off, bbase);
    k_fill<<<(N_EDGES + 255) / 256, 256, 0, stream>>>(src, dst, off, cnt, csrc);

    const int init_blocks = (N_NODES * 32 + 255) / 256;
    const int prop_blocks = (N_NODES + 3) / 4;
    const int gemm_blocks = (N_NODES + 31) / 32;

    // ---- layer 1 ----
    k_init<<<init_blocks, 256, 0, stream>>>(feat, norm, bufA);
    k_prop<<<prop_blocks, 256, 0, stream>>>(bufA, off, csrc, norm, Xsum, bufB, 0);
    k_prop<<<prop_blocks, 256, 0, stream>>>(bufB, off, csrc, norm, Xsum, nullptr, 1);
    // out = relu((feat + Xsum)W1 + 3b1); bufA = out*norm (layer-2 gather input)
    k_gemm_relu<<<gemm_blocks, 256, 0, stream>>>(feat, Xsum, W1, b1, out, bufA, norm, 3.0f);

    // ---- layer 2 ----
    k_prop<<<prop_blocks, 256, 0, stream>>>(bufA, off, csrc, norm, Xsum, bufB, 0);
    k_prop<<<prop_blocks, 256, 0, stream>>>(bufB, off, csrc, norm, Xsum, nullptr, 1);
    k_gemm_relu<<<gemm_blocks, 256, 0, stream>>>(out, Xsum, W2, b2, out, nullptr, norm, 3.0f);
}

// Round 4
// 404.529 us; speedup vs baseline: 1.6479x; 1.1604x over previous
//
#include <hip/hip_runtime.h>

#define N_NODES 50000
#define N_EDGES 800000
#define D 128
#define NSB ((N_NODES + 255) / 256)   // 196 scan blocks

typedef unsigned short ushort_t;
typedef unsigned int uint_t;

__device__ __forceinline__ float bf2f(ushort_t u) {
    uint_t x = ((uint_t)u) << 16;
    return __builtin_bit_cast(float, x);
}
__device__ __forceinline__ ushort_t f2bf(float f) {
    uint_t u = __builtin_bit_cast(uint_t, f);
    uint_t r = (u + 0x7FFFu + ((u >> 16) & 1u)) >> 16;   // round-to-nearest-even
    return (ushort_t)r;
}

// ---------------- degrees + dst-rank in one pass (2 atomics/edge) ----------------
__global__ void k_build(const int* __restrict__ src, const int* __restrict__ dst,
                        int* __restrict__ outdeg, int* __restrict__ indeg,
                        int* __restrict__ pos) {
    int e = blockIdx.x * blockDim.x + threadIdx.x;
    if (e < N_EDGES) {
        atomicAdd(&outdeg[src[e]], 1);
        pos[e] = atomicAdd(&indeg[dst[e]], 1);
    }
}

// ---------------- two-level exclusive scan of indeg -> off; fused norm ----------------
__global__ void k_scanA(const int* __restrict__ indeg, int* __restrict__ off,
                        int* __restrict__ bsum,
                        const int* __restrict__ outdeg, float* __restrict__ norm) {
    __shared__ int sh[256];
    int t = threadIdx.x;
    int i = blockIdx.x * 256 + t;
    int v = (i < N_NODES) ? indeg[i] : 0;
    sh[t] = v;
    __syncthreads();
    for (int d = 1; d < 256; d <<= 1) {
        int x = sh[t];
        int y = (t >= d) ? sh[t - d] : 0;
        __syncthreads();
        sh[t] = x + y;
        __syncthreads();
    }
    if (i < N_NODES) {
        off[i] = sh[t] - v;                       // exclusive within block
        float dg = (float)outdeg[i];
        norm[i] = 1.0f / sqrtf(fmaxf(dg, 1.0f));
    }
    if (t == 255) bsum[blockIdx.x] = sh[255];
}

__global__ void k_scanB(const int* __restrict__ bsum, int* __restrict__ bbase,
                        int* __restrict__ off) {
    __shared__ int sh[256];
    int t = threadIdx.x;
    int v = (t < NSB) ? bsum[t] : 0;
    sh[t] = v;
    __syncthreads();
    for (int d = 1; d < 256; d <<= 1) {
        int x = sh[t];
        int y = (t >= d) ? sh[t - d] : 0;
        __syncthreads();
        sh[t] = x + y;
        __syncthreads();
    }
    if (t < NSB) bbase[t] = sh[t] - v;
    if (t == 255) off[N_NODES] = sh[255];
}

__global__ void k_scanC(int* __restrict__ off, const int* __restrict__ bbase) {
    int i = blockIdx.x * 256 + threadIdx.x;
    if (i < N_NODES) off[i] += bbase[blockIdx.x];
}

// ---------------- atomic-free CSR fill ----------------
__global__ void k_scatter(const int* __restrict__ src, const int* __restrict__ dst,
                          const int* __restrict__ off, const int* __restrict__ pos,
                          int* __restrict__ csrc) {
    int e = blockIdx.x * blockDim.x + threadIdx.x;
    if (e < N_EDGES) csrc[off[dst[e]] + pos[e]] = src[e];
}

// ---------------- layer-1 init: A = bf16(X * norm) ----------------
__global__ void k_init(const float* __restrict__ X, const float* __restrict__ norm,
                       ushort_t* __restrict__ A) {
    int i = blockIdx.x * blockDim.x + threadIdx.x;  // float4 / ushort4 index
    const int total = N_NODES * (D / 4);
    if (i < total) {
        int row = i >> 5;
        float4 v = ((const float4*)X)[i];
        float nm = norm[row];
        ushort4 a = {f2bf(v.x * nm), f2bf(v.y * nm), f2bf(v.z * nm), f2bf(v.w * nm)};
        ((ushort4*)A)[i] = a;
    }
}

// ---------------- propagation hop: one wave per node, paired bf16 gathers ----
// X = (sum_{e: dst==node} Ain[src[e]]) * norm[node]
// accum ? Xsum += X : Xsum = X;   if (Anext) Anext = bf16(X * norm)
__global__ __launch_bounds__(256) void k_prop(const ushort_t* __restrict__ Ain,
                       const int* __restrict__ off, const int* __restrict__ csrc,
                       const float* __restrict__ norm,
                       float* __restrict__ Xsum, ushort_t* __restrict__ Anext,
                       int accum) {
    int w = blockIdx.x * 4 + (threadIdx.x >> 6);
    if (w >= N_NODES) return;
    int lane = threadIdx.x & 63;
    int half = lane >> 5;          // lanes 0-31: even edges; 32-63: odd edges
    int c4 = lane & 31;            // 4-element group within the 128-wide row
    int s0 = off[w], s1 = off[w + 1];
    float4 acc = {0.f, 0.f, 0.f, 0.f};
    const ushort4* A4 = (const ushort4*)Ain;
    // 16 edges per iteration: 8 paired 512B gather instructions in flight
    for (int j = s0; j < s1; j += 16) {
#pragma unroll
        for (int k = 0; k < 8; ++k) {
            int jj = j + 2 * k + half;
            int jc = jj < s1 ? jj : s0;          // safe: loop entered only if s1>s0
            int s = csrc[jc];
            ushort4 v = A4[(size_t)s * 32 + c4];
            if (jj < s1) {
                acc.x += bf2f(v.x); acc.y += bf2f(v.y);
                acc.z += bf2f(v.z); acc.w += bf2f(v.w);
            }
        }
    }
    // combine the two half-wave partial sums
    acc.x += __shfl_xor(acc.x, 32);
    acc.y += __shfl_xor(acc.y, 32);
    acc.z += __shfl_xor(acc.z, 32);
    acc.w += __shfl_xor(acc.w, 32);
    float nm = norm[w];
    float4 X = {acc.x * nm, acc.y * nm, acc.z * nm, acc.w * nm};
    size_t base = (size_t)w * 32 + c4;
    if (half == 0) {
        float4 o = X;
        if (accum) {
            float4 sv = ((float4*)Xsum)[base];
            o.x += sv.x; o.y += sv.y; o.z += sv.z; o.w += sv.w;
        }
        ((float4*)Xsum)[base] = o;
    } else if (Anext) {
        ushort4 b = {f2bf(X.x * nm), f2bf(X.y * nm), f2bf(X.z * nm), f2bf(X.w * nm)};
        ((ushort4*)Anext)[base] = b;
    }
}

// ---- out = relu((X0+Xsum) @ W + bscale*bias); opt Anext = bf16(out*norm) ----
__global__ __launch_bounds__(256) void k_gemm_relu(const float* __restrict__ X0,
        const float* __restrict__ Xsum,
        const float* __restrict__ W, const float* __restrict__ bias,
        float* __restrict__ out, ushort_t* __restrict__ Anext,
        const float* __restrict__ norm, float bscale) {
    __shared__ float As[32 * 128];   // 16 KB
    int t = threadIdx.x;
    int row0 = blockIdx.x * 32;
    float4* As4 = (float4*)As;
    for (int i = t; i < 32 * 32; i += 256) {
        int r = row0 + (i >> 5);
        float4 v = {0.f, 0.f, 0.f, 0.f};
        if (r < N_NODES) {
            float4 a = ((const float4*)X0)[(size_t)r * 32 + (i & 31)];
            float4 b = ((const float4*)Xsum)[(size_t)r * 32 + (i & 31)];
            v.x = a.x + b.x; v.y = a.y + b.y; v.z = a.z + b.z; v.w = a.w + b.w;
        }
        As4[i] = v;
    }
    __syncthreads();
    int r0 = (t >> 5) * 4;     // 4 rows per thread
    int c4 = t & 31;           // float4 column group
    float acc[4][4] = {};
    const float4* W4 = (const float4*)W;
#pragma unroll 2
    for (int k4 = 0; k4 < 32; ++k4) {
        float4 wv[4];
#pragma unroll
        for (int kk = 0; kk < 4; ++kk) wv[kk] = W4[(size_t)(k4 * 4 + kk) * 32 + c4];
        float4 av[4];
#pragma unroll
        for (int i = 0; i < 4; ++i) av[i] = As4[(r0 + i) * 32 + k4];
#pragma unroll
        for (int i = 0; i < 4; ++i) {
            acc[i][0] += av[i].x * wv[0].x + av[i].y * wv[1].x + av[i].z * wv[2].x + av[i].w * wv[3].x;
            acc[i][1] += av[i].x * wv[0].y + av[i].y * wv[1].y + av[i].z * wv[2].y + av[i].w * wv[3].y;
            acc[i][2] += av[i].x * wv[0].z + av[i].y * wv[1].z + av[i].z * wv[2].z + av[i].w * wv[3].z;
            acc[i][3] += av[i].x * wv[0].w + av[i].y * wv[1].w + av[i].z * wv[2].w + av[i].w * wv[3].w;
        }
    }
    float4 bv = ((const float4*)bias)[c4];
    bv.x *= bscale; bv.y *= bscale; bv.z *= bscale; bv.w *= bscale;
#pragma unroll
    for (int i = 0; i < 4; ++i) {
        int r = row0 + r0 + i;
        if (r < N_NODES) {
            float4 o;
            o.x = fmaxf(acc[i][0] + bv.x, 0.f);
            o.y = fmaxf(acc[i][1] + bv.y, 0.f);
            o.z = fmaxf(acc[i][2] + bv.z, 0.f);
            o.w = fmaxf(acc[i][3] + bv.w, 0.f);
            ((float4*)out)[(size_t)r * 32 + c4] = o;
            if (Anext) {
                float nm = norm[r];
                ushort4 a = {f2bf(o.x * nm), f2bf(o.y * nm), f2bf(o.z * nm), f2bf(o.w * nm)};
                ((ushort4*)Anext)[(size_t)r * 32 + c4] = a;
            }
        }
    }
}

extern "C" void kernel_launch(void* const* d_in, const int* in_sizes, int n_in,
                              void* d_out, int out_size, void* d_ws, size_t ws_size,
                              hipStream_t stream) {
    const float* feat = (const float*)d_in[0];
    const float* W1   = (const float*)d_in[1];
    const float* b1   = (const float*)d_in[2];
    const float* W2   = (const float*)d_in[3];
    const float* b2   = (const float*)d_in[4];
    const int*   src  = (const int*)d_in[5];
    const int*   dst  = (const int*)d_in[6];
    float* out = (float*)d_out;

    char* ws = (char*)d_ws;
    size_t o = 0;
    auto alloc = [&](size_t bytes) {
        void* p = ws + o;
        o += (bytes + 1023) & ~(size_t)1023;
        return p;
    };
    int*      outdeg = (int*)alloc(N_NODES * 4);   // outdeg+indeg contiguous: one memset
    int*      indeg  = (int*)alloc(N_NODES * 4);
    float*    norm   = (float*)alloc(N_NODES * 4);
    int*      off    = (int*)alloc((N_NODES + 1) * 4);
    int*      bsum   = (int*)alloc(NSB * 4);
    int*      bbase  = (int*)alloc(NSB * 4);
    int*      pos    = (int*)alloc((size_t)N_EDGES * 4);
    int*      csrc   = (int*)alloc((size_t)N_EDGES * 4);
    ushort_t* bufA   = (ushort_t*)alloc((size_t)N_NODES * D * 2);
    ushort_t* bufB   = (ushort_t*)alloc((size_t)N_NODES * D * 2);
    float*    Xsum   = (float*)alloc((size_t)N_NODES * D * 4);
    (void)ws_size; (void)in_sizes; (void)n_in; (void)out_size;

    const size_t pad = ((size_t)N_NODES * 4 + 1023) & ~(size_t)1023;
    hipMemsetAsync(outdeg, 0, pad * 2, stream);

    k_build<<<(N_EDGES + 255) / 256, 256, 0, stream>>>(src, dst, outdeg, indeg, pos);
    k_scanA<<<NSB, 256, 0, stream>>>(indeg, off, bsum, outdeg, norm);
    k_scanB<<<1, 256, 0, stream>>>(bsum, bbase, off);
    k_scanC<<<NSB, 256, 0, stream>>>(off, bbase);
    k_scatter<<<(N_EDGES + 255) / 256, 256, 0, stream>>>(src, dst, off, pos, csrc);

    const int init_blocks = (N_NODES * 32 + 255) / 256;
    const int prop_blocks = (N_NODES + 3) / 4;
    const int gemm_blocks = (N_NODES + 31) / 32;

    // ---- layer 1 ----
    k_init<<<init_blocks, 256, 0, stream>>>(feat, norm, bufA);
    k_prop<<<prop_blocks, 256, 0, stream>>>(bufA, off, csrc, norm, Xsum, bufB, 0);
    k_prop<<<prop_blocks, 256, 0, stream>>>(bufB, off, csrc, norm, Xsum, nullptr, 1);
    // out = relu((feat + Xsum)W1 + 3b1); bufA = bf16(out*norm) for layer-2 gathers
    k_gemm_relu<<<gemm_blocks, 256, 0, stream>>>(feat, Xsum, W1, b1, out, bufA, norm, 3.0f);

    // ---- layer 2 ----
    k_prop<<<prop_blocks, 256, 0, stream>>>(bufA, off, csrc, norm, Xsum, bufB, 0);
    k_prop<<<prop_blocks, 256, 0, stream>>>(bufB, off, csrc, norm, Xsum, nullptr, 1);
    k_gemm_relu<<<gemm_blocks, 256, 0, stream>>>(out, Xsum, W2, b2, out, nullptr, norm, 3.0f);
}

// Round 5
// 379.031 us; speedup vs baseline: 1.7588x; 1.0673x over previous
//
#include <hip/hip_runtime.h>

#define N_NODES 50000
#define N_EDGES 800000
#define D 128
#define NSB ((N_NODES + 255) / 256)   // 196 scan blocks
#define NCH 32                         // edge chunks
#define EPC (N_EDGES / NCH)            // 25000 edges per chunk
#define NR 8                           // node ranges
#define RNG (N_NODES / NR)             // 6250 nodes per range

typedef unsigned short ushort_t;
typedef unsigned int uint_t;

__device__ __forceinline__ float bf2f(ushort_t u) {
    uint_t x = ((uint_t)u) << 16;
    return __builtin_bit_cast(float, x);
}
__device__ __forceinline__ ushort_t f2bf(float f) {
    uint_t u = __builtin_bit_cast(uint_t, f);
    uint_t r = (u + 0x7FFFu + ((u >> 16) & 1u)) >> 16;   // round-to-nearest-even
    return (ushort_t)r;
}

// ---- LDS-privatized per-chunk histograms + within-chunk dst-rank (no global atomics) ----
__global__ __launch_bounds__(256) void kb_hist(const int* __restrict__ src,
        const int* __restrict__ dst, int* __restrict__ srchist,
        int* __restrict__ dsthist, int* __restrict__ lrank) {
    __shared__ int hs[RNG];
    __shared__ int hd[RNG];
    int chunk = blockIdx.x, range = blockIdx.y;
    int base = range * RNG;
    int t = threadIdx.x;
    for (int i = t; i < RNG; i += 256) { hs[i] = 0; hd[i] = 0; }
    __syncthreads();
    int e0 = chunk * EPC;
    for (int e = e0 + t; e < e0 + EPC; e += 256) {
        int s = src[e], d = dst[e];
        unsigned su = (unsigned)(s - base), du = (unsigned)(d - base);
        if (su < RNG) atomicAdd(&hs[su], 1);
        if (du < RNG) lrank[e] = atomicAdd(&hd[du], 1);
    }
    __syncthreads();
    int* os = srchist + (size_t)chunk * N_NODES + base;
    int* od = dsthist + (size_t)chunk * N_NODES + base;
    for (int i = t; i < RNG; i += 256) { os[i] = hs[i]; od[i] = hd[i]; }
}

// ---- per-node: indeg + exclusive chunk prefix (in-place), outdeg -> norm ----
__global__ void kb_reduce(int* __restrict__ dsthist, const int* __restrict__ srchist,
                          int* __restrict__ indeg, float* __restrict__ norm) {
    int n = blockIdx.x * 256 + threadIdx.x;
    if (n >= N_NODES) return;
    int run = 0;
#pragma unroll
    for (int c = 0; c < NCH; ++c) {
        size_t idx = (size_t)c * N_NODES + n;
        int v = dsthist[idx];
        dsthist[idx] = run;           // becomes chunkbase
        run += v;
    }
    indeg[n] = run;
    int od = 0;
#pragma unroll
    for (int c = 0; c < NCH; ++c) od += srchist[(size_t)c * N_NODES + n];
    norm[n] = 1.0f / sqrtf(fmaxf((float)od, 1.0f));
}

// ---------------- two-level exclusive scan of indeg -> off ----------------
__global__ void k_scanA(const int* __restrict__ indeg, int* __restrict__ off,
                        int* __restrict__ bsum) {
    __shared__ int sh[256];
    int t = threadIdx.x;
    int i = blockIdx.x * 256 + t;
    int v = (i < N_NODES) ? indeg[i] : 0;
    sh[t] = v;
    __syncthreads();
    for (int d = 1; d < 256; d <<= 1) {
        int x = sh[t];
        int y = (t >= d) ? sh[t - d] : 0;
        __syncthreads();
        sh[t] = x + y;
        __syncthreads();
    }
    if (i < N_NODES) off[i] = sh[t] - v;
    if (t == 255) bsum[blockIdx.x] = sh[255];
}

__global__ void k_scanB(const int* __restrict__ bsum, int* __restrict__ bbase,
                        int* __restrict__ off) {
    __shared__ int sh[256];
    int t = threadIdx.x;
    int v = (t < NSB) ? bsum[t] : 0;
    sh[t] = v;
    __syncthreads();
    for (int d = 1; d < 256; d <<= 1) {
        int x = sh[t];
        int y = (t >= d) ? sh[t - d] : 0;
        __syncthreads();
        sh[t] = x + y;
        __syncthreads();
    }
    if (t < NSB) bbase[t] = sh[t] - v;
    if (t == 255) off[N_NODES] = sh[255];
}

__global__ void k_scanC(int* __restrict__ off, const int* __restrict__ bbase) {
    int i = blockIdx.x * 256 + threadIdx.x;
    if (i < N_NODES) off[i] += bbase[blockIdx.x];
}

// ---------------- atomic-free CSR fill ----------------
__global__ void kb_scatter(const int* __restrict__ src, const int* __restrict__ dst,
                           const int* __restrict__ off, const int* __restrict__ chunkbase,
                           const int* __restrict__ lrank, int* __restrict__ csrc) {
    int e = blockIdx.x * blockDim.x + threadIdx.x;
    if (e < N_EDGES) {
        int d = dst[e];
        int chunk = e / EPC;
        int p = off[d] + chunkbase[(size_t)chunk * N_NODES + d] + lrank[e];
        csrc[p] = src[e];
    }
}

// ---------------- layer-1 init: A = bf16(X * norm) ----------------
__global__ void k_init(const float* __restrict__ X, const float* __restrict__ norm,
                       ushort_t* __restrict__ A) {
    int i = blockIdx.x * blockDim.x + threadIdx.x;  // float4 / ushort4 index
    const int total = N_NODES * (D / 4);
    if (i < total) {
        int row = i >> 5;
        float4 v = ((const float4*)X)[i];
        float nm = norm[row];
        ushort4 a = {f2bf(v.x * nm), f2bf(v.y * nm), f2bf(v.z * nm), f2bf(v.w * nm)};
        ((ushort4*)A)[i] = a;
    }
}

// ---------------- propagation hop: one wave per node, paired bf16 gathers ----
// X = (sum_{e: dst==node} Ain[src[e]]) * norm[node]
// accum ? Xsum += X : Xsum = X;   if (Anext) Anext = bf16(X * norm)
__global__ __launch_bounds__(256) void k_prop(const ushort_t* __restrict__ Ain,
                       const int* __restrict__ off, const int* __restrict__ csrc,
                       const float* __restrict__ norm,
                       float* __restrict__ Xsum, ushort_t* __restrict__ Anext,
                       int accum) {
    int w = blockIdx.x * 4 + (threadIdx.x >> 6);
    if (w >= N_NODES) return;
    int lane = threadIdx.x & 63;
    int half = lane >> 5;          // lanes 0-31: even edges; 32-63: odd edges
    int c4 = lane & 31;            // 4-element group within the 128-wide row
    int s0 = off[w], s1 = off[w + 1];
    float4 acc = {0.f, 0.f, 0.f, 0.f};
    const ushort4* A4 = (const ushort4*)Ain;
    // 16 edges per iteration: 8 paired 512B gather instructions in flight
    for (int j = s0; j < s1; j += 16) {
#pragma unroll
        for (int k = 0; k < 8; ++k) {
            int jj = j + 2 * k + half;
            int jc = jj < s1 ? jj : s0;          // safe: loop entered only if s1>s0
            int s = csrc[jc];
            ushort4 v = A4[(size_t)s * 32 + c4];
            if (jj < s1) {
                acc.x += bf2f(v.x); acc.y += bf2f(v.y);
                acc.z += bf2f(v.z); acc.w += bf2f(v.w);
            }
        }
    }
    // combine the two half-wave partial sums
    acc.x += __shfl_xor(acc.x, 32);
    acc.y += __shfl_xor(acc.y, 32);
    acc.z += __shfl_xor(acc.z, 32);
    acc.w += __shfl_xor(acc.w, 32);
    float nm = norm[w];
    float4 X = {acc.x * nm, acc.y * nm, acc.z * nm, acc.w * nm};
    size_t base = (size_t)w * 32 + c4;
    if (half == 0) {
        float4 o = X;
        if (accum) {
            float4 sv = ((float4*)Xsum)[base];
            o.x += sv.x; o.y += sv.y; o.z += sv.z; o.w += sv.w;
        }
        ((float4*)Xsum)[base] = o;
    } else if (Anext) {
        ushort4 b = {f2bf(X.x * nm), f2bf(X.y * nm), f2bf(X.z * nm), f2bf(X.w * nm)};
        ((ushort4*)Anext)[base] = b;
    }
}

// ---- out = relu((X0+Xsum) @ W + bscale*bias); opt Anext = bf16(out*norm) ----
__global__ __launch_bounds__(256) void k_gemm_relu(const float* __restrict__ X0,
        const float* __restrict__ Xsum,
        const float* __restrict__ W, const float* __restrict__ bias,
        float* __restrict__ out, ushort_t* __restrict__ Anext,
        const float* __restrict__ norm, float bscale) {
    __shared__ float As[32 * 128];   // 16 KB
    int t = threadIdx.x;
    int row0 = blockIdx.x * 32;
    float4* As4 = (float4*)As;
    for (int i = t; i < 32 * 32; i += 256) {
        int r = row0 + (i >> 5);
        float4 v = {0.f, 0.f, 0.f, 0.f};
        if (r < N_NODES) {
            float4 a = ((const float4*)X0)[(size_t)r * 32 + (i & 31)];
            float4 b = ((const float4*)Xsum)[(size_t)r * 32 + (i & 31)];
            v.x = a.x + b.x; v.y = a.y + b.y; v.z = a.z + b.z; v.w = a.w + b.w;
        }
        As4[i] = v;
    }
    __syncthreads();
    int r0 = (t >> 5) * 4;     // 4 rows per thread
    int c4 = t & 31;           // float4 column group
    float acc[4][4] = {};
    const float4* W4 = (const float4*)W;
#pragma unroll 2
    for (int k4 = 0; k4 < 32; ++k4) {
        float4 wv[4];
#pragma unroll
        for (int kk = 0; kk < 4; ++kk) wv[kk] = W4[(size_t)(k4 * 4 + kk) * 32 + c4];
        float4 av[4];
#pragma unroll
        for (int i = 0; i < 4; ++i) av[i] = As4[(r0 + i) * 32 + k4];
#pragma unroll
        for (int i = 0; i < 4; ++i) {
            acc[i][0] += av[i].x * wv[0].x + av[i].y * wv[1].x + av[i].z * wv[2].x + av[i].w * wv[3].x;
            acc[i][1] += av[i].x * wv[0].y + av[i].y * wv[1].y + av[i].z * wv[2].y + av[i].w * wv[3].y;
            acc[i][2] += av[i].x * wv[0].z + av[i].y * wv[1].z + av[i].z * wv[2].z + av[i].w * wv[3].z;
            acc[i][3] += av[i].x * wv[0].w + av[i].y * wv[1].w + av[i].z * wv[2].w + av[i].w * wv[3].w;
        }
    }
    float4 bv = ((const float4*)bias)[c4];
    bv.x *= bscale; bv.y *= bscale; bv.z *= bscale; bv.w *= bscale;
#pragma unroll
    for (int i = 0; i < 4; ++i) {
        int r = row0 + r0 + i;
        if (r < N_NODES) {
            float4 o;
            o.x = fmaxf(acc[i][0] + bv.x, 0.f);
            o.y = fmaxf(acc[i][1] + bv.y, 0.f);
            o.z = fmaxf(acc[i][2] + bv.z, 0.f);
            o.w = fmaxf(acc[i][3] + bv.w, 0.f);
            ((float4*)out)[(size_t)r * 32 + c4] = o;
            if (Anext) {
                float nm = norm[r];
                ushort4 a = {f2bf(o.x * nm), f2bf(o.y * nm), f2bf(o.z * nm), f2bf(o.w * nm)};
                ((ushort4*)Anext)[(size_t)r * 32 + c4] = a;
            }
        }
    }
}

extern "C" void kernel_launch(void* const* d_in, const int* in_sizes, int n_in,
                              void* d_out, int out_size, void* d_ws, size_t ws_size,
                              hipStream_t stream) {
    const float* feat = (const float*)d_in[0];
    const float* W1   = (const float*)d_in[1];
    const float* b1   = (const float*)d_in[2];
    const float* W2   = (const float*)d_in[3];
    const float* b2   = (const float*)d_in[4];
    const int*   src  = (const int*)d_in[5];
    const int*   dst  = (const int*)d_in[6];
    float* out = (float*)d_out;

    char* ws = (char*)d_ws;
    size_t o = 0;
    auto alloc = [&](size_t bytes) {
        void* p = ws + o;
        o += (bytes + 1023) & ~(size_t)1023;
        return p;
    };
    int*      srchist = (int*)alloc((size_t)NCH * N_NODES * 4);   // 6.4 MB
    int*      dsthist = (int*)alloc((size_t)NCH * N_NODES * 4);   // 6.4 MB (-> chunkbase)
    int*      lrank   = (int*)alloc((size_t)N_EDGES * 4);
    int*      indeg   = (int*)alloc(N_NODES * 4);
    float*    norm    = (float*)alloc(N_NODES * 4);
    int*      off     = (int*)alloc((N_NODES + 1) * 4);
    int*      bsum    = (int*)alloc(NSB * 4);
    int*      bbase   = (int*)alloc(NSB * 4);
    int*      csrc    = (int*)alloc((size_t)N_EDGES * 4);
    ushort_t* bufA    = (ushort_t*)alloc((size_t)N_NODES * D * 2);
    ushort_t* bufB    = (ushort_t*)alloc((size_t)N_NODES * D * 2);
    float*    Xsum    = (float*)alloc((size_t)N_NODES * D * 4);
    (void)ws_size; (void)in_sizes; (void)n_in; (void)out_size;

    kb_hist<<<dim3(NCH, NR), 256, 0, stream>>>(src, dst, srchist, dsthist, lrank);
    kb_reduce<<<(N_NODES + 255) / 256, 256, 0, stream>>>(dsthist, srchist, indeg, norm);
    k_scanA<<<NSB, 256, 0, stream>>>(indeg, off, bsum);
    k_scanB<<<1, 256, 0, stream>>>(bsum, bbase, off);
    k_scanC<<<NSB, 256, 0, stream>>>(off, bbase);
    kb_scatter<<<(N_EDGES + 255) / 256, 256, 0, stream>>>(src, dst, off, dsthist, lrank, csrc);

    const int init_blocks = (N_NODES * 32 + 255) / 256;
    const int prop_blocks = (N_NODES + 3) / 4;
    const int gemm_blocks = (N_NODES + 31) / 32;

    // ---- layer 1 ----
    k_init<<<init_blocks, 256, 0, stream>>>(feat, norm, bufA);
    k_prop<<<prop_blocks, 256, 0, stream>>>(bufA, off, csrc, norm, Xsum, bufB, 0);
    k_prop<<<prop_blocks, 256, 0, stream>>>(bufB, off, csrc, norm, Xsum, nullptr, 1);
    // out = relu((feat + Xsum)W1 + 3b1); bufA = bf16(out*norm) for layer-2 gathers
    k_gemm_relu<<<gemm_blocks, 256, 0, stream>>>(feat, Xsum, W1, b1, out, bufA, norm, 3.0f);

    // ---- layer 2 ----
    k_prop<<<prop_blocks, 256, 0, stream>>>(bufA, off, csrc, norm, Xsum, bufB, 0);
    k_prop<<<prop_blocks, 256, 0, stream>>>(bufB, off, csrc, norm, Xsum, nullptr, 1);
    k_gemm_relu<<<gemm_blocks, 256, 0, stream>>>(out, Xsum, W2, b2, out, nullptr, norm, 3.0f);
}

// Round 6
// 366.386 us; speedup vs baseline: 1.8195x; 1.0345x over previous
//
#include <hip/hip_runtime.h>

#define N_NODES 50000
#define N_EDGES 800000
#define D 128
#define NSB ((N_NODES + 255) / 256)   // 196 scan blocks
#define NCH 64                         // edge chunks
#define EPC (N_EDGES / NCH)            // 12500 edges per chunk
#define NR 8                           // node ranges
#define RNG (N_NODES / NR)             // 6250 nodes per range

typedef unsigned short ushort_t;
typedef unsigned int uint_t;

__device__ __forceinline__ float bf2f(ushort_t u) {
    uint_t x = ((uint_t)u) << 16;
    return __builtin_bit_cast(float, x);
}
__device__ __forceinline__ ushort_t f2bf(float f) {
    uint_t u = __builtin_bit_cast(uint_t, f);
    uint_t r = (u + 0x7FFFu + ((u >> 16) & 1u)) >> 16;   // round-to-nearest-even
    return (ushort_t)r;
}

// ---- pass 1: packed per-chunk histograms (dst in lo16, src in hi16), no returns ----
__global__ __launch_bounds__(256) void kb_hist(const int* __restrict__ src,
        const int* __restrict__ dst, uint_t* __restrict__ hist) {
    __shared__ uint_t h[RNG];          // 25 KB
    int chunk = blockIdx.x, range = blockIdx.y;
    int base = range * RNG;
    int t = threadIdx.x;
    for (int i = t; i < RNG; i += 256) h[i] = 0;
    __syncthreads();
    int e0 = chunk * EPC;
    for (int e = e0 + t; e < e0 + EPC; e += 256) {
        unsigned su = (unsigned)(src[e] - base);
        unsigned du = (unsigned)(dst[e] - base);
        if (su < RNG) atomicAdd(&h[su], 1u << 16);
        if (du < RNG) atomicAdd(&h[du], 1u);
    }
    __syncthreads();
    uint_t* oh = hist + (size_t)chunk * N_NODES + base;
    for (int i = t; i < RNG; i += 256) oh[i] = h[i];
}

// ---- per node: indeg, chunkbase (in-place), outdeg -> norm, rnorm ----
__global__ void kb_reduce(uint_t* __restrict__ hist, int* __restrict__ indeg,
                          float* __restrict__ norm, float* __restrict__ rnorm) {
    int n = blockIdx.x * 256 + threadIdx.x;
    if (n >= N_NODES) return;
    int run = 0, od = 0;
#pragma unroll
    for (int c = 0; c < NCH; ++c) {
        size_t idx = (size_t)c * N_NODES + n;
        uint_t v = hist[idx];
        hist[idx] = (uint_t)run;       // becomes within-node dst chunk-prefix
        run += (int)(v & 0xFFFFu);
        od  += (int)(v >> 16);
    }
    indeg[n] = run;
    float dg = fmaxf((float)od, 1.0f);
    norm[n]  = 1.0f / sqrtf(dg);
    rnorm[n] = sqrtf(dg);
}

// ---------------- two-level exclusive scan of indeg -> off ----------------
__global__ void k_scanA(const int* __restrict__ indeg, int* __restrict__ off,
                        int* __restrict__ bsum) {
    __shared__ int sh[256];
    int t = threadIdx.x;
    int i = blockIdx.x * 256 + t;
    int v = (i < N_NODES) ? indeg[i] : 0;
    sh[t] = v;
    __syncthreads();
    for (int d = 1; d < 256; d <<= 1) {
        int x = sh[t];
        int y = (t >= d) ? sh[t - d] : 0;
        __syncthreads();
        sh[t] = x + y;
        __syncthreads();
    }
    if (i < N_NODES) off[i] = sh[t] - v;
    if (t == 255) bsum[blockIdx.x] = sh[255];
}

__global__ void k_scanB(const int* __restrict__ bsum, int* __restrict__ bbase,
                        int* __restrict__ off) {
    __shared__ int sh[256];
    int t = threadIdx.x;
    int v = (t < NSB) ? bsum[t] : 0;
    sh[t] = v;
    __syncthreads();
    for (int d = 1; d < 256; d <<= 1) {
        int x = sh[t];
        int y = (t >= d) ? sh[t - d] : 0;
        __syncthreads();
        sh[t] = x + y;
        __syncthreads();
    }
    if (t < NSB) bbase[t] = sh[t] - v;
    if (t == 255) off[N_NODES] = sh[255];
}

__global__ void k_scanC(int* __restrict__ off, const int* __restrict__ bbase) {
    int i = blockIdx.x * 256 + threadIdx.x;
    if (i < N_NODES) off[i] += bbase[blockIdx.x];
}

// ---- pass 2: regenerate ranks in LDS, scatter csrc (no global atomics) ----
__global__ __launch_bounds__(256) void kb_scatter(const int* __restrict__ src,
        const int* __restrict__ dst, const int* __restrict__ off,
        const uint_t* __restrict__ hist, int* __restrict__ csrc) {
    __shared__ int slot[RNG];          // 25 KB
    int chunk = blockIdx.x, range = blockIdx.y;
    int base = range * RNG;
    int t = threadIdx.x;
    const uint_t* hb = hist + (size_t)chunk * N_NODES + base;
    for (int i = t; i < RNG; i += 256) slot[i] = off[base + i] + (int)hb[i];
    __syncthreads();
    int e0 = chunk * EPC;
    for (int e = e0 + t; e < e0 + EPC; e += 256) {
        unsigned du = (unsigned)(dst[e] - base);
        if (du < RNG) {
            int p = atomicAdd(&slot[du], 1);
            csrc[p] = src[e];
        }
    }
}

// ---------------- layer-1 init: A = bf16(X * norm) ----------------
__global__ void k_init(const float* __restrict__ X, const float* __restrict__ norm,
                       ushort_t* __restrict__ A) {
    int i = blockIdx.x * blockDim.x + threadIdx.x;  // float4 / ushort4 index
    const int total = N_NODES * (D / 4);
    if (i < total) {
        int row = i >> 5;
        float4 v = ((const float4*)X)[i];
        float nm = norm[row];
        ushort4 a = {f2bf(v.x * nm), f2bf(v.y * nm), f2bf(v.z * nm), f2bf(v.w * nm)};
        ((ushort4*)A)[i] = a;
    }
}

// ---- propagation hop: acc = sum gathers; Aout = bf16(acc * (mode? norm : norm^2)) ----
// mode 0 (hop 1): writes A1 = X1*norm    (gather input for hop 2; X1 = A1*rnorm)
// mode 1 (hop 2): writes X2 directly
__global__ __launch_bounds__(256) void k_prop(const ushort_t* __restrict__ Ain,
                       const int* __restrict__ off, const int* __restrict__ csrc,
                       const float* __restrict__ norm,
                       ushort_t* __restrict__ Aout, int mode) {
    int w = blockIdx.x * 4 + (threadIdx.x >> 6);
    if (w >= N_NODES) return;
    int lane = threadIdx.x & 63;
    int half = lane >> 5;          // lanes 0-31: even edges; 32-63: odd edges
    int c4 = lane & 31;            // 4-element group within the 128-wide row
    int s0 = off[w], s1 = off[w + 1];
    float4 acc = {0.f, 0.f, 0.f, 0.f};
    const ushort4* A4 = (const ushort4*)Ain;
    // 16 edges per iteration: 8 paired 512B gather instructions in flight
    for (int j = s0; j < s1; j += 16) {
#pragma unroll
        for (int k = 0; k < 8; ++k) {
            int jj = j + 2 * k + half;
            int jc = jj < s1 ? jj : s0;          // safe: loop entered only if s1>s0
            int s = csrc[jc];
            ushort4 v = A4[(size_t)s * 32 + c4];
            if (jj < s1) {
                acc.x += bf2f(v.x); acc.y += bf2f(v.y);
                acc.z += bf2f(v.z); acc.w += bf2f(v.w);
            }
        }
    }
    acc.x += __shfl_xor(acc.x, 32);
    acc.y += __shfl_xor(acc.y, 32);
    acc.z += __shfl_xor(acc.z, 32);
    acc.w += __shfl_xor(acc.w, 32);
    if (half == 0) {
        float nm = norm[w];
        float f = mode ? nm : nm * nm;
        ushort4 b = {f2bf(acc.x * f), f2bf(acc.y * f), f2bf(acc.z * f), f2bf(acc.w * f)};
        ((ushort4*)Aout)[(size_t)w * 32 + c4] = b;
    }
}

// ---- out = relu((X0 + A1*rnorm + X2) @ W + bscale*bias); opt Anext = bf16(out*norm) ----
__global__ __launch_bounds__(256) void k_gemm_relu(const float* __restrict__ X0,
        const ushort_t* __restrict__ A1, const ushort_t* __restrict__ X2,
        const float* __restrict__ rnorm,
        const float* __restrict__ W, const float* __restrict__ bias,
        float* __restrict__ out, ushort_t* __restrict__ Anext,
        const float* __restrict__ norm, float bscale) {
    __shared__ float As[32 * 128];   // 16 KB
    int t = threadIdx.x;
    int row0 = blockIdx.x * 32;
    float4* As4 = (float4*)As;
    for (int i = t; i < 32 * 32; i += 256) {
        int r = row0 + (i >> 5);
        float4 v = {0.f, 0.f, 0.f, 0.f};
        if (r < N_NODES) {
            size_t idx = (size_t)r * 32 + (i & 31);
            float4 a = ((const float4*)X0)[idx];
            ushort4 u1 = ((const ushort4*)A1)[idx];
            ushort4 u2 = ((const ushort4*)X2)[idx];
            float rn = rnorm[r];
            v.x = a.x + bf2f(u1.x) * rn + bf2f(u2.x);
            v.y = a.y + bf2f(u1.y) * rn + bf2f(u2.y);
            v.z = a.z + bf2f(u1.z) * rn + bf2f(u2.z);
            v.w = a.w + bf2f(u1.w) * rn + bf2f(u2.w);
        }
        As4[i] = v;
    }
    __syncthreads();
    int r0 = (t >> 5) * 4;     // 4 rows per thread
    int c4 = t & 31;           // float4 column group
    float acc[4][4] = {};
    const float4* W4 = (const float4*)W;
#pragma unroll 2
    for (int k4 = 0; k4 < 32; ++k4) {
        float4 wv[4];
#pragma unroll
        for (int kk = 0; kk < 4; ++kk) wv[kk] = W4[(size_t)(k4 * 4 + kk) * 32 + c4];
        float4 av[4];
#pragma unroll
        for (int i = 0; i < 4; ++i) av[i] = As4[(r0 + i) * 32 + k4];
#pragma unroll
        for (int i = 0; i < 4; ++i) {
            acc[i][0] += av[i].x * wv[0].x + av[i].y * wv[1].x + av[i].z * wv[2].x + av[i].w * wv[3].x;
            acc[i][1] += av[i].x * wv[0].y + av[i].y * wv[1].y + av[i].z * wv[2].y + av[i].w * wv[3].y;
            acc[i][2] += av[i].x * wv[0].z + av[i].y * wv[1].z + av[i].z * wv[2].z + av[i].w * wv[3].z;
            acc[i][3] += av[i].x * wv[0].w + av[i].y * wv[1].w + av[i].z * wv[2].w + av[i].w * wv[3].w;
        }
    }
    float4 bv = ((const float4*)bias)[c4];
    bv.x *= bscale; bv.y *= bscale; bv.z *= bscale; bv.w *= bscale;
#pragma unroll
    for (int i = 0; i < 4; ++i) {
        int r = row0 + r0 + i;
        if (r < N_NODES) {
            float4 o;
            o.x = fmaxf(acc[i][0] + bv.x, 0.f);
            o.y = fmaxf(acc[i][1] + bv.y, 0.f);
            o.z = fmaxf(acc[i][2] + bv.z, 0.f);
            o.w = fmaxf(acc[i][3] + bv.w, 0.f);
            ((float4*)out)[(size_t)r * 32 + c4] = o;
            if (Anext) {
                float nm = norm[r];
                ushort4 a = {f2bf(o.x * nm), f2bf(o.y * nm), f2bf(o.z * nm), f2bf(o.w * nm)};
                ((ushort4*)Anext)[(size_t)r * 32 + c4] = a;
            }
        }
    }
}

extern "C" void kernel_launch(void* const* d_in, const int* in_sizes, int n_in,
                              void* d_out, int out_size, void* d_ws, size_t ws_size,
                              hipStream_t stream) {
    const float* feat = (const float*)d_in[0];
    const float* W1   = (const float*)d_in[1];
    const float* b1   = (const float*)d_in[2];
    const float* W2   = (const float*)d_in[3];
    const float* b2   = (const float*)d_in[4];
    const int*   src  = (const int*)d_in[5];
    const int*   dst  = (const int*)d_in[6];
    float* out = (float*)d_out;

    char* ws = (char*)d_ws;
    size_t o = 0;
    auto alloc = [&](size_t bytes) {
        void* p = ws + o;
        o += (bytes + 1023) & ~(size_t)1023;
        return p;
    };
    uint_t*   hist  = (uint_t*)alloc((size_t)NCH * N_NODES * 4);   // 12.8 MB
    int*      indeg = (int*)alloc(N_NODES * 4);
    float*    norm  = (float*)alloc(N_NODES * 4);
    float*    rnorm = (float*)alloc(N_NODES * 4);
    int*      off   = (int*)alloc((N_NODES + 1) * 4);
    int*      bsum  = (int*)alloc(NSB * 4);
    int*      bbase = (int*)alloc(NSB * 4);
    int*      csrc  = (int*)alloc((size_t)N_EDGES * 4);
    ushort_t* bufA  = (ushort_t*)alloc((size_t)N_NODES * D * 2);   // A0
    ushort_t* bufB  = (ushort_t*)alloc((size_t)N_NODES * D * 2);   // A1
    ushort_t* bufC  = (ushort_t*)alloc((size_t)N_NODES * D * 2);   // X2
    (void)ws_size; (void)in_sizes; (void)n_in; (void)out_size;

    kb_hist<<<dim3(NCH, NR), 256, 0, stream>>>(src, dst, hist);
    kb_reduce<<<(N_NODES + 255) / 256, 256, 0, stream>>>(hist, indeg, norm, rnorm);
    k_scanA<<<NSB, 256, 0, stream>>>(indeg, off, bsum);
    k_scanB<<<1, 256, 0, stream>>>(bsum, bbase, off);
    k_scanC<<<NSB, 256, 0, stream>>>(off, bbase);
    kb_scatter<<<dim3(NCH, NR), 256, 0, stream>>>(src, dst, off, hist, csrc);

    const int init_blocks = (N_NODES * 32 + 255) / 256;
    const int prop_blocks = (N_NODES + 3) / 4;
    const int gemm_blocks = (N_NODES + 31) / 32;

    // ---- layer 1 ----
    k_init<<<init_blocks, 256, 0, stream>>>(feat, norm, bufA);                 // A0
    k_prop<<<prop_blocks, 256, 0, stream>>>(bufA, off, csrc, norm, bufB, 0);   // A1
    k_prop<<<prop_blocks, 256, 0, stream>>>(bufB, off, csrc, norm, bufC, 1);   // X2
    // out = relu((feat + A1*rnorm + X2)W1 + 3b1); bufA = bf16(out*norm) for layer 2
    k_gemm_relu<<<gemm_blocks, 256, 0, stream>>>(feat, bufB, bufC, rnorm, W1, b1,
                                                 out, bufA, norm, 3.0f);

    // ---- layer 2 ----
    k_prop<<<prop_blocks, 256, 0, stream>>>(bufA, off, csrc, norm, bufB, 0);   // A1
    k_prop<<<prop_blocks, 256, 0, stream>>>(bufB, off, csrc, norm, bufC, 1);   // X2
    k_gemm_relu<<<gemm_blocks, 256, 0, stream>>>(out, bufB, bufC, rnorm, W2, b2,
                                                 out, nullptr, norm, 3.0f);
}

// Round 7
// 280.482 us; speedup vs baseline: 2.3767x; 1.3063x over previous
//
#include <hip/hip_runtime.h>

#define N_NODES 50000
#define N_EDGES 800000
#define D 128
#define NSB ((N_NODES + 255) / 256)   // 196 scan blocks
#define NCH 64                         // edge chunks
#define EPC (N_EDGES / NCH)            // 12500 edges per chunk
#define NR 8                           // node ranges
#define RNG (N_NODES / NR)             // 6250 nodes per range

typedef unsigned short ushort_t;
typedef unsigned int uint_t;
typedef short s16x8 __attribute__((ext_vector_type(8)));
typedef float f32x4 __attribute__((ext_vector_type(4)));

__device__ __forceinline__ float bf2f(ushort_t u) {
    uint_t x = ((uint_t)u) << 16;
    return __builtin_bit_cast(float, x);
}
__device__ __forceinline__ ushort_t f2bf(float f) {
    uint_t u = __builtin_bit_cast(uint_t, f);
    uint_t r = (u + 0x7FFFu + ((u >> 16) & 1u)) >> 16;   // round-to-nearest-even
    return (ushort_t)r;
}

// ---- pass 1: packed per-chunk histograms (dst in lo16, src in hi16) ----
__global__ __launch_bounds__(256) void kb_hist(const int* __restrict__ src,
        const int* __restrict__ dst, uint_t* __restrict__ hist) {
    __shared__ uint_t h[RNG];          // 25 KB
    int chunk = blockIdx.x, range = blockIdx.y;
    int base = range * RNG;
    int t = threadIdx.x;
    for (int i = t; i < RNG; i += 256) h[i] = 0;
    __syncthreads();
    int e0 = chunk * EPC;
    for (int e = e0 + t; e < e0 + EPC; e += 256) {
        unsigned su = (unsigned)(src[e] - base);
        unsigned du = (unsigned)(dst[e] - base);
        if (su < RNG) atomicAdd(&h[su], 1u << 16);
        if (du < RNG) atomicAdd(&h[du], 1u);
    }
    __syncthreads();
    uint_t* oh = hist + (size_t)chunk * N_NODES + base;
    for (int i = t; i < RNG; i += 256) oh[i] = h[i];
}

// ---- per node: indeg, chunkbase (in-place), outdeg -> norm, rnorm ----
__global__ void kb_reduce(uint_t* __restrict__ hist, int* __restrict__ indeg,
                          float* __restrict__ norm, float* __restrict__ rnorm) {
    int n = blockIdx.x * 256 + threadIdx.x;
    if (n >= N_NODES) return;
    int run = 0, od = 0;
#pragma unroll
    for (int c = 0; c < NCH; ++c) {
        size_t idx = (size_t)c * N_NODES + n;
        uint_t v = hist[idx];
        hist[idx] = (uint_t)run;       // becomes within-node dst chunk-prefix
        run += (int)(v & 0xFFFFu);
        od  += (int)(v >> 16);
    }
    indeg[n] = run;
    float dg = fmaxf((float)od, 1.0f);
    norm[n]  = 1.0f / sqrtf(dg);
    rnorm[n] = sqrtf(dg);
}

// ---------------- two-level exclusive scan of indeg -> off ----------------
__global__ void k_scanA(const int* __restrict__ indeg, int* __restrict__ off,
                        int* __restrict__ bsum) {
    __shared__ int sh[256];
    int t = threadIdx.x;
    int i = blockIdx.x * 256 + t;
    int v = (i < N_NODES) ? indeg[i] : 0;
    sh[t] = v;
    __syncthreads();
    for (int d = 1; d < 256; d <<= 1) {
        int x = sh[t];
        int y = (t >= d) ? sh[t - d] : 0;
        __syncthreads();
        sh[t] = x + y;
        __syncthreads();
    }
    if (i < N_NODES) off[i] = sh[t] - v;
    if (t == 255) bsum[blockIdx.x] = sh[255];
}

__global__ void k_scanB(const int* __restrict__ bsum, int* __restrict__ bbase,
                        int* __restrict__ off) {
    __shared__ int sh[256];
    int t = threadIdx.x;
    int v = (t < NSB) ? bsum[t] : 0;
    sh[t] = v;
    __syncthreads();
    for (int d = 1; d < 256; d <<= 1) {
        int x = sh[t];
        int y = (t >= d) ? sh[t - d] : 0;
        __syncthreads();
        sh[t] = x + y;
        __syncthreads();
    }
    if (t < NSB) bbase[t] = sh[t] - v;
    if (t == 255) off[N_NODES] = sh[255];
}

__global__ void k_scanC(int* __restrict__ off, const int* __restrict__ bbase) {
    int i = blockIdx.x * 256 + threadIdx.x;
    if (i < N_NODES) off[i] += bbase[blockIdx.x];
}

// ---- pass 2: regenerate ranks in LDS, scatter csrc (no global atomics) ----
__global__ __launch_bounds__(256) void kb_scatter(const int* __restrict__ src,
        const int* __restrict__ dst, const int* __restrict__ off,
        const uint_t* __restrict__ hist, int* __restrict__ csrc) {
    __shared__ int slot[RNG];          // 25 KB
    int chunk = blockIdx.x, range = blockIdx.y;
    int base = range * RNG;
    int t = threadIdx.x;
    const uint_t* hb = hist + (size_t)chunk * N_NODES + base;
    for (int i = t; i < RNG; i += 256) slot[i] = off[base + i] + (int)hb[i];
    __syncthreads();
    int e0 = chunk * EPC;
    for (int e = e0 + t; e < e0 + EPC; e += 256) {
        unsigned du = (unsigned)(dst[e] - base);
        if (du < RNG) {
            int p = atomicAdd(&slot[du], 1);
            csrc[p] = src[e];
        }
    }
}

// ---- W transpose + bf16: Wt[col][k] = bf16(W[k][col]) ----
__global__ void k_prepw(const float* __restrict__ W, ushort_t* __restrict__ Wt) {
    int i = blockIdx.x * 256 + threadIdx.x;
    if (i < D * D) {
        int col = i >> 7, k = i & 127;
        Wt[i] = f2bf(W[(size_t)k * D + col]);
    }
}

// ---------------- layer-1 init: A = bf16(X * norm) ----------------
__global__ void k_init(const float* __restrict__ X, const float* __restrict__ norm,
                       ushort_t* __restrict__ A) {
    int i = blockIdx.x * blockDim.x + threadIdx.x;  // float4 / ushort4 index
    const int total = N_NODES * (D / 4);
    if (i < total) {
        int row = i >> 5;
        float4 v = ((const float4*)X)[i];
        float nm = norm[row];
        ushort4 a = {f2bf(v.x * nm), f2bf(v.y * nm), f2bf(v.z * nm), f2bf(v.w * nm)};
        ((ushort4*)A)[i] = a;
    }
}

// ---- propagation hop: 16-lane group per node, b128 gathers, 8-edge unroll ----
// mode 0 (hop 1): Aout = bf16(acc * norm^2) = A1 ; mode 1 (hop 2): Aout = bf16(acc*norm) = X2
__global__ __launch_bounds__(256) void k_prop(const ushort_t* __restrict__ Ain,
                       const int* __restrict__ off, const int* __restrict__ csrc,
                       const float* __restrict__ norm,
                       ushort_t* __restrict__ Aout, int mode) {
    int w = blockIdx.x * 16 + (threadIdx.x >> 4);
    if (w >= N_NODES) return;
    int li = threadIdx.x & 15;         // 16B chunk within the 256B row
    int s0 = off[w], s1 = off[w + 1];
    float a0=0.f,a1=0.f,a2=0.f,a3=0.f,a4=0.f,a5=0.f,a6=0.f,a7=0.f;
    const s16x8* A8 = (const s16x8*)Ain;
    for (int j = s0; j < s1; j += 8) {
#pragma unroll
        for (int k = 0; k < 8; ++k) {
            int jj = j + k;
            int jc = jj < s1 ? jj : s1 - 1;   // clamp: wasted fetch is L1-hot
            int s = csrc[jc];
            s16x8 v = A8[(size_t)s * 16 + li];
            if (jj < s1) {
                a0 += bf2f((ushort_t)v[0]); a1 += bf2f((ushort_t)v[1]);
                a2 += bf2f((ushort_t)v[2]); a3 += bf2f((ushort_t)v[3]);
                a4 += bf2f((ushort_t)v[4]); a5 += bf2f((ushort_t)v[5]);
                a6 += bf2f((ushort_t)v[6]); a7 += bf2f((ushort_t)v[7]);
            }
        }
    }
    float nm = norm[w];
    float f = mode ? nm : nm * nm;
    s16x8 o;
    o[0] = (short)f2bf(a0 * f); o[1] = (short)f2bf(a1 * f);
    o[2] = (short)f2bf(a2 * f); o[3] = (short)f2bf(a3 * f);
    o[4] = (short)f2bf(a4 * f); o[5] = (short)f2bf(a5 * f);
    o[6] = (short)f2bf(a6 * f); o[7] = (short)f2bf(a7 * f);
    ((s16x8*)Aout)[(size_t)w * 16 + li] = o;
}

// ---- MFMA gemm: out = relu((X0 + A1*rnorm + X2) @ W + bscale*bias) ----
// Wt is bf16 [col][k]. Optional Anext = bf16(out*norm).
__global__ __launch_bounds__(256) void k_gemm_relu(const float* __restrict__ X0,
        const ushort_t* __restrict__ A1, const ushort_t* __restrict__ X2,
        const float* __restrict__ rnorm,
        const ushort_t* __restrict__ Wt, const float* __restrict__ bias,
        float* __restrict__ out, ushort_t* __restrict__ Anext,
        const float* __restrict__ norm, float bscale) {
    __shared__ ushort_t Xs[64 * D];    // 16 KB, swizzled 16B chunks
    __shared__ ushort_t Ws[D * D];     // 32 KB, swizzled
    int t = threadIdx.x;
    int row0 = blockIdx.x * 64;
    // stage Wt -> Ws (swizzle chunk: pc = c ^ (row&7))
    const s16x8* Wg = (const s16x8*)Wt;
    s16x8* Ws8 = (s16x8*)Ws;
    for (int i = t; i < D * 16; i += 256) {
        int col = i >> 4, c = i & 15;
        Ws8[(col << 4) | (c ^ (col & 7))] = Wg[i];
    }
    // stage X = X0 + A1*rnorm + X2 -> bf16 swizzled
    s16x8* Xs8 = (s16x8*)Xs;
    for (int i = t; i < 64 * 16; i += 256) {
        int r = i >> 4, c = i & 15;    // chunk c: cols c*8..c*8+7
        int gr = row0 + r;
        s16x8 ov;
        if (gr < N_NODES) {
            size_t b4 = (size_t)gr * 32 + c * 2;
            float4  x0a = ((const float4*)X0)[b4], x0b = ((const float4*)X0)[b4 + 1];
            ushort4 p0 = ((const ushort4*)A1)[b4], p1 = ((const ushort4*)A1)[b4 + 1];
            ushort4 q0 = ((const ushort4*)X2)[b4], q1 = ((const ushort4*)X2)[b4 + 1];
            float rn = rnorm[gr];
            ov[0] = (short)f2bf(x0a.x + bf2f(p0.x) * rn + bf2f(q0.x));
            ov[1] = (short)f2bf(x0a.y + bf2f(p0.y) * rn + bf2f(q0.y));
            ov[2] = (short)f2bf(x0a.z + bf2f(p0.z) * rn + bf2f(q0.z));
            ov[3] = (short)f2bf(x0a.w + bf2f(p0.w) * rn + bf2f(q0.w));
            ov[4] = (short)f2bf(x0b.x + bf2f(p1.x) * rn + bf2f(q1.x));
            ov[5] = (short)f2bf(x0b.y + bf2f(p1.y) * rn + bf2f(q1.y));
            ov[6] = (short)f2bf(x0b.z + bf2f(p1.z) * rn + bf2f(q1.z));
            ov[7] = (short)f2bf(x0b.w + bf2f(p1.w) * rn + bf2f(q1.w));
        } else {
            ov = (s16x8)0;
        }
        Xs8[(r << 4) | (c ^ (r & 7))] = ov;
    }
    __syncthreads();
    int wid = t >> 6, l = t & 63;
    int lrow = l & 15, lk = l >> 4;    // lk: k-group (8 bf16 each)
    f32x4 acc[8];
#pragma unroll
    for (int nt = 0; nt < 8; ++nt) acc[nt] = (f32x4){0.f, 0.f, 0.f, 0.f};
    const s16x8* Xr = (const s16x8*)Xs;
    const s16x8* Wr = (const s16x8*)Ws;
#pragma unroll
    for (int ks = 0; ks < 4; ++ks) {
        int kc = ks * 4 + lk;          // 16B chunk along k (k = kc*8)
        int ar = wid * 16 + lrow;      // A row
        s16x8 a = Xr[(ar << 4) | (kc ^ (ar & 7))];
#pragma unroll
        for (int nt = 0; nt < 8; ++nt) {
            int bc = nt * 16 + lrow;   // B col
            s16x8 b = Wr[(bc << 4) | (kc ^ (bc & 7))];
            acc[nt] = __builtin_amdgcn_mfma_f32_16x16x32_bf16(a, b, acc[nt], 0, 0, 0);
        }
    }
    // epilogue: C/D layout col = l&15, row = (l>>4)*4 + reg
    int rbase = row0 + wid * 16 + lk * 4;
#pragma unroll
    for (int nt = 0; nt < 8; ++nt) {
        int C = nt * 16 + lrow;
        float bv = bias[C] * bscale;
#pragma unroll
        for (int r = 0; r < 4; ++r) {
            int R = rbase + r;
            if (R < N_NODES) {
                float o = fmaxf(acc[nt][r] + bv, 0.f);
                out[(size_t)R * D + C] = o;
                if (Anext) Anext[(size_t)R * D + C] = f2bf(o * norm[R]);
            }
        }
    }
}

extern "C" void kernel_launch(void* const* d_in, const int* in_sizes, int n_in,
                              void* d_out, int out_size, void* d_ws, size_t ws_size,
                              hipStream_t stream) {
    const float* feat = (const float*)d_in[0];
    const float* W1   = (const float*)d_in[1];
    const float* b1   = (const float*)d_in[2];
    const float* W2   = (const float*)d_in[3];
    const float* b2   = (const float*)d_in[4];
    const int*   src  = (const int*)d_in[5];
    const int*   dst  = (const int*)d_in[6];
    float* out = (float*)d_out;

    char* ws = (char*)d_ws;
    size_t o = 0;
    auto alloc = [&](size_t bytes) {
        void* p = ws + o;
        o += (bytes + 1023) & ~(size_t)1023;
        return p;
    };
    uint_t*   hist  = (uint_t*)alloc((size_t)NCH * N_NODES * 4);   // 12.8 MB
    int*      indeg = (int*)alloc(N_NODES * 4);
    float*    norm  = (float*)alloc(N_NODES * 4);
    float*    rnorm = (float*)alloc(N_NODES * 4);
    int*      off   = (int*)alloc((N_NODES + 1) * 4);
    int*      bsum  = (int*)alloc(NSB * 4);
    int*      bbase = (int*)alloc(NSB * 4);
    int*      csrc  = (int*)alloc((size_t)N_EDGES * 4);
    ushort_t* bufA  = (ushort_t*)alloc((size_t)N_NODES * D * 2);   // A0
    ushort_t* bufB  = (ushort_t*)alloc((size_t)N_NODES * D * 2);   // A1
    ushort_t* bufC  = (ushort_t*)alloc((size_t)N_NODES * D * 2);   // X2
    ushort_t* Wt1   = (ushort_t*)alloc((size_t)D * D * 2);
    ushort_t* Wt2   = (ushort_t*)alloc((size_t)D * D * 2);
    (void)ws_size; (void)in_sizes; (void)n_in; (void)out_size;

    kb_hist<<<dim3(NCH, NR), 256, 0, stream>>>(src, dst, hist);
    kb_reduce<<<(N_NODES + 255) / 256, 256, 0, stream>>>(hist, indeg, norm, rnorm);
    k_scanA<<<NSB, 256, 0, stream>>>(indeg, off, bsum);
    k_scanB<<<1, 256, 0, stream>>>(bsum, bbase, off);
    k_scanC<<<NSB, 256, 0, stream>>>(off, bbase);
    kb_scatter<<<dim3(NCH, NR), 256, 0, stream>>>(src, dst, off, hist, csrc);
    k_prepw<<<(D * D + 255) / 256, 256, 0, stream>>>(W1, Wt1);
    k_prepw<<<(D * D + 255) / 256, 256, 0, stream>>>(W2, Wt2);

    const int init_blocks = (N_NODES * 32 + 255) / 256;
    const int prop_blocks = (N_NODES + 15) / 16;
    const int gemm_blocks = (N_NODES + 63) / 64;

    // ---- layer 1 ----
    k_init<<<init_blocks, 256, 0, stream>>>(feat, norm, bufA);                 // A0
    k_prop<<<prop_blocks, 256, 0, stream>>>(bufA, off, csrc, norm, bufB, 0);   // A1
    k_prop<<<prop_blocks, 256, 0, stream>>>(bufB, off, csrc, norm, bufC, 1);   // X2
    k_gemm_relu<<<gemm_blocks, 256, 0, stream>>>(feat, bufB, bufC, rnorm, Wt1, b1,
                                                 out, bufA, norm, 3.0f);

    // ---- layer 2 ----
    k_prop<<<prop_blocks, 256, 0, stream>>>(bufA, off, csrc, norm, bufB, 0);   // A1
    k_prop<<<prop_blocks, 256, 0, stream>>>(bufB, off, csrc, norm, bufC, 1);   // X2
    k_gemm_relu<<<gemm_blocks, 256, 0, stream>>>(out, bufB, bufC, rnorm, Wt2, b2,
                                                 out, nullptr, norm, 3.0f);
}

// Round 8
// 227.253 us; speedup vs baseline: 2.9334x; 1.2342x over previous
//
#include <hip/hip_runtime.h>

#define N_NODES 50000
#define N_EDGES 800000
#define D 128
#define NSB ((N_NODES + 255) / 256)   // 196 scan blocks
#define NCH 128                        // edge chunks
#define EPC (N_EDGES / NCH)            // 6250 edges per chunk
#define NR 8                           // node ranges
#define RNG (N_NODES / NR)             // 6250 nodes per range

typedef unsigned short ushort_t;
typedef unsigned int uint_t;
typedef short s16x8 __attribute__((ext_vector_type(8)));
typedef float f32x4 __attribute__((ext_vector_type(4)));

__device__ __forceinline__ float bf2f(ushort_t u) {
    uint_t x = ((uint_t)u) << 16;
    return __builtin_bit_cast(float, x);
}
__device__ __forceinline__ ushort_t f2bf(float f) {
    uint_t u = __builtin_bit_cast(uint_t, f);
    uint_t r = (u + 0x7FFFu + ((u >> 16) & 1u)) >> 16;   // round-to-nearest-even
    return (ushort_t)r;
}

// ---- pass 1: packed per-chunk histograms (dst in lo16, src in hi16) ----
__global__ __launch_bounds__(256) void kb_hist(const int* __restrict__ src,
        const int* __restrict__ dst, uint_t* __restrict__ hist) {
    __shared__ uint_t h[RNG];          // 25 KB
    int chunk = blockIdx.x, range = blockIdx.y;
    int base = range * RNG;
    int t = threadIdx.x;
    for (int i = t; i < RNG; i += 256) h[i] = 0;
    __syncthreads();
    int e0 = chunk * EPC;
    for (int e = e0 + t; e < e0 + EPC; e += 256) {
        unsigned su = (unsigned)(src[e] - base);
        unsigned du = (unsigned)(dst[e] - base);
        if (su < RNG) atomicAdd(&h[su], 1u << 16);
        if (du < RNG) atomicAdd(&h[du], 1u);
    }
    __syncthreads();
    uint_t* oh = hist + (size_t)chunk * N_NODES + base;
    for (int i = t; i < RNG; i += 256) oh[i] = h[i];
}

// ---- per node: indeg, chunkbase (in-place), outdeg -> norm, rnorm ----
__global__ void kb_reduce(uint_t* __restrict__ hist, int* __restrict__ indeg,
                          float* __restrict__ norm, float* __restrict__ rnorm) {
    int n = blockIdx.x * 256 + threadIdx.x;
    if (n >= N_NODES) return;
    int run = 0, od = 0;
#pragma unroll 8
    for (int c = 0; c < NCH; ++c) {
        size_t idx = (size_t)c * N_NODES + n;
        uint_t v = hist[idx];
        hist[idx] = (uint_t)run;       // becomes within-node dst chunk-prefix
        run += (int)(v & 0xFFFFu);
        od  += (int)(v >> 16);
    }
    indeg[n] = run;
    float dg = fmaxf((float)od, 1.0f);
    norm[n]  = 1.0f / sqrtf(dg);
    rnorm[n] = sqrtf(dg);
}

// ---------------- two-level exclusive scan of indeg -> off ----------------
__global__ void k_scanA(const int* __restrict__ indeg, int* __restrict__ off,
                        int* __restrict__ bsum) {
    __shared__ int sh[256];
    int t = threadIdx.x;
    int i = blockIdx.x * 256 + t;
    int v = (i < N_NODES) ? indeg[i] : 0;
    sh[t] = v;
    __syncthreads();
    for (int d = 1; d < 256; d <<= 1) {
        int x = sh[t];
        int y = (t >= d) ? sh[t - d] : 0;
        __syncthreads();
        sh[t] = x + y;
        __syncthreads();
    }
    if (i < N_NODES) off[i] = sh[t] - v;
    if (t == 255) bsum[blockIdx.x] = sh[255];
}

__global__ void k_scanB(const int* __restrict__ bsum, int* __restrict__ bbase,
                        int* __restrict__ off) {
    __shared__ int sh[256];
    int t = threadIdx.x;
    int v = (t < NSB) ? bsum[t] : 0;
    sh[t] = v;
    __syncthreads();
    for (int d = 1; d < 256; d <<= 1) {
        int x = sh[t];
        int y = (t >= d) ? sh[t - d] : 0;
        __syncthreads();
        sh[t] = x + y;
        __syncthreads();
    }
    if (t < NSB) bbase[t] = sh[t] - v;
    if (t == 255) off[N_NODES] = sh[255];
}

__global__ void k_scanC(int* __restrict__ off, const int* __restrict__ bbase) {
    int i = blockIdx.x * 256 + threadIdx.x;
    if (i < N_NODES) off[i] += bbase[blockIdx.x];
}

// ---- pass 2: regenerate ranks in LDS, scatter csrc (no global atomics) ----
__global__ __launch_bounds__(256) void kb_scatter(const int* __restrict__ src,
        const int* __restrict__ dst, const int* __restrict__ off,
        const uint_t* __restrict__ hist, int* __restrict__ csrc) {
    __shared__ int slot[RNG];          // 25 KB
    int chunk = blockIdx.x, range = blockIdx.y;
    int base = range * RNG;
    int t = threadIdx.x;
    const uint_t* hb = hist + (size_t)chunk * N_NODES + base;
    for (int i = t; i < RNG; i += 256) slot[i] = off[base + i] + (int)hb[i];
    __syncthreads();
    int e0 = chunk * EPC;
    for (int e = e0 + t; e < e0 + EPC; e += 256) {
        unsigned du = (unsigned)(dst[e] - base);
        if (du < RNG) {
            int p = atomicAdd(&slot[du], 1);
            csrc[p] = src[e];
        }
    }
}

// ---- W transpose + bf16: Wt[col][k] = bf16(W[k][col]) ----
__global__ void k_prepw(const float* __restrict__ W, ushort_t* __restrict__ Wt) {
    int i = blockIdx.x * 256 + threadIdx.x;
    if (i < D * D) {
        int col = i >> 7, k = i & 127;
        Wt[i] = f2bf(W[(size_t)k * D + col]);
    }
}

// ---------------- layer-1 init: A = bf16(X * norm) ----------------
__global__ void k_init(const float* __restrict__ X, const float* __restrict__ norm,
                       ushort_t* __restrict__ A) {
    int i = blockIdx.x * blockDim.x + threadIdx.x;  // float4 / ushort4 index
    const int total = N_NODES * (D / 4);
    if (i < total) {
        int row = i >> 5;
        float4 v = ((const float4*)X)[i];
        float nm = norm[row];
        ushort4 a = {f2bf(v.x * nm), f2bf(v.y * nm), f2bf(v.z * nm), f2bf(v.w * nm)};
        ((ushort4*)A)[i] = a;
    }
}

// ---- propagation hop: 16-lane group per node, 16 b128 gathers in flight ----
// mode 0 (hop 1): Aout = bf16(acc * norm^2) = A1 ; mode 1 (hop 2): Aout = bf16(acc*norm) = X2
__global__ __launch_bounds__(256, 2) void k_prop(const ushort_t* __restrict__ Ain,
                       const int* __restrict__ off, const int* __restrict__ csrc,
                       const float* __restrict__ norm,
                       ushort_t* __restrict__ Aout, int mode) {
    int w = blockIdx.x * 16 + (threadIdx.x >> 4);
    if (w >= N_NODES) return;
    int li = threadIdx.x & 15;         // 16B chunk within the 256B row
    int s0 = off[w], s1 = off[w + 1];
    float a0=0.f,a1=0.f,a2=0.f,a3=0.f,a4=0.f,a5=0.f,a6=0.f,a7=0.f;
    const s16x8* A8 = (const s16x8*)Ain;
    int j = s0;
    // main loop: 16 independent row gathers in flight
    for (; j + 16 <= s1; j += 16) {
        int idx[16];
#pragma unroll
        for (int k = 0; k < 16; ++k) idx[k] = csrc[j + k];
        s16x8 v[16];
#pragma unroll
        for (int k = 0; k < 16; ++k) v[k] = A8[(size_t)idx[k] * 16 + li];
#pragma unroll
        for (int k = 0; k < 16; ++k) {
            a0 += bf2f((ushort_t)v[k][0]); a1 += bf2f((ushort_t)v[k][1]);
            a2 += bf2f((ushort_t)v[k][2]); a3 += bf2f((ushort_t)v[k][3]);
            a4 += bf2f((ushort_t)v[k][4]); a5 += bf2f((ushort_t)v[k][5]);
            a6 += bf2f((ushort_t)v[k][6]); a7 += bf2f((ushort_t)v[k][7]);
        }
    }
    // weighted tail (clamped loads are L1-hot; weight 0 kills contribution)
    if (j < s1) {
        int e1 = s1 - 1;
        for (; j < s1; j += 8) {
            int idx[8]; float wk[8];
#pragma unroll
            for (int k = 0; k < 8; ++k) {
                int jj = j + k;
                idx[k] = csrc[jj < s1 ? jj : e1];
                wk[k] = (jj < s1) ? 1.f : 0.f;
            }
            s16x8 v[8];
#pragma unroll
            for (int k = 0; k < 8; ++k) v[k] = A8[(size_t)idx[k] * 16 + li];
#pragma unroll
            for (int k = 0; k < 8; ++k) {
                a0 = fmaf(wk[k], bf2f((ushort_t)v[k][0]), a0);
                a1 = fmaf(wk[k], bf2f((ushort_t)v[k][1]), a1);
                a2 = fmaf(wk[k], bf2f((ushort_t)v[k][2]), a2);
                a3 = fmaf(wk[k], bf2f((ushort_t)v[k][3]), a3);
                a4 = fmaf(wk[k], bf2f((ushort_t)v[k][4]), a4);
                a5 = fmaf(wk[k], bf2f((ushort_t)v[k][5]), a5);
                a6 = fmaf(wk[k], bf2f((ushort_t)v[k][6]), a6);
                a7 = fmaf(wk[k], bf2f((ushort_t)v[k][7]), a7);
            }
        }
    }
    float nm = norm[w];
    float f = mode ? nm : nm * nm;
    s16x8 o;
    o[0] = (short)f2bf(a0 * f); o[1] = (short)f2bf(a1 * f);
    o[2] = (short)f2bf(a2 * f); o[3] = (short)f2bf(a3 * f);
    o[4] = (short)f2bf(a4 * f); o[5] = (short)f2bf(a5 * f);
    o[6] = (short)f2bf(a6 * f); o[7] = (short)f2bf(a7 * f);
    ((s16x8*)Aout)[(size_t)w * 16 + li] = o;
}

// ---- MFMA gemm: out = relu((X0 + A1*rnorm + X2) @ W + bscale*bias) ----
// X0 from X0f (f32) or X0h (bf16). Outputs any of: outf (f32), Hbf (bf16), Anext (bf16*norm).
__global__ __launch_bounds__(256) void k_gemm_relu(const float* __restrict__ X0f,
        const ushort_t* __restrict__ X0h,
        const ushort_t* __restrict__ A1, const ushort_t* __restrict__ X2,
        const float* __restrict__ rnorm,
        const ushort_t* __restrict__ Wt, const float* __restrict__ bias,
        float* __restrict__ outf, ushort_t* __restrict__ Hbf,
        ushort_t* __restrict__ Anext,
        const float* __restrict__ norm, float bscale) {
    __shared__ ushort_t Xs[64 * D];    // 16 KB, swizzled 16B chunks
    __shared__ ushort_t Ws[D * D];     // 32 KB, swizzled
    int t = threadIdx.x;
    int row0 = blockIdx.x * 64;
    // stage Wt -> Ws (swizzle chunk: pc = c ^ (row&7))
    const s16x8* Wg = (const s16x8*)Wt;
    s16x8* Ws8 = (s16x8*)Ws;
    for (int i = t; i < D * 16; i += 256) {
        int col = i >> 4, c = i & 15;
        Ws8[(col << 4) | (c ^ (col & 7))] = Wg[i];
    }
    // stage X = X0 + A1*rnorm + X2 -> bf16 swizzled
    s16x8* Xs8 = (s16x8*)Xs;
    for (int i = t; i < 64 * 16; i += 256) {
        int r = i >> 4, c = i & 15;    // chunk c: cols c*8..c*8+7
        int gr = row0 + r;
        s16x8 ov;
        if (gr < N_NODES) {
            size_t b4 = (size_t)gr * 32 + c * 2;
            float x[8];
            if (X0f) {
                float4 x0a = ((const float4*)X0f)[b4], x0b = ((const float4*)X0f)[b4 + 1];
                x[0]=x0a.x; x[1]=x0a.y; x[2]=x0a.z; x[3]=x0a.w;
                x[4]=x0b.x; x[5]=x0b.y; x[6]=x0b.z; x[7]=x0b.w;
            } else {
                ushort4 h0 = ((const ushort4*)X0h)[b4], h1 = ((const ushort4*)X0h)[b4 + 1];
                x[0]=bf2f(h0.x); x[1]=bf2f(h0.y); x[2]=bf2f(h0.z); x[3]=bf2f(h0.w);
                x[4]=bf2f(h1.x); x[5]=bf2f(h1.y); x[6]=bf2f(h1.z); x[7]=bf2f(h1.w);
            }
            ushort4 p0 = ((const ushort4*)A1)[b4], p1 = ((const ushort4*)A1)[b4 + 1];
            ushort4 q0 = ((const ushort4*)X2)[b4], q1 = ((const ushort4*)X2)[b4 + 1];
            float rn = rnorm[gr];
            ov[0] = (short)f2bf(x[0] + bf2f(p0.x) * rn + bf2f(q0.x));
            ov[1] = (short)f2bf(x[1] + bf2f(p0.y) * rn + bf2f(q0.y));
            ov[2] = (short)f2bf(x[2] + bf2f(p0.z) * rn + bf2f(q0.z));
            ov[3] = (short)f2bf(x[3] + bf2f(p0.w) * rn + bf2f(q0.w));
            ov[4] = (short)f2bf(x[4] + bf2f(p1.x) * rn + bf2f(q1.x));
            ov[5] = (short)f2bf(x[5] + bf2f(p1.y) * rn + bf2f(q1.y));
            ov[6] = (short)f2bf(x[6] + bf2f(p1.z) * rn + bf2f(q1.z));
            ov[7] = (short)f2bf(x[7] + bf2f(p1.w) * rn + bf2f(q1.w));
        } else {
            ov = (s16x8)0;
        }
        Xs8[(r << 4) | (c ^ (r & 7))] = ov;
    }
    __syncthreads();
    int wid = t >> 6, l = t & 63;
    int lrow = l & 15, lk = l >> 4;    // lk: k-group (8 bf16 each)
    f32x4 acc[8];
#pragma unroll
    for (int nt = 0; nt < 8; ++nt) acc[nt] = (f32x4){0.f, 0.f, 0.f, 0.f};
    const s16x8* Xr = (const s16x8*)Xs;
    const s16x8* Wr = (const s16x8*)Ws;
#pragma unroll
    for (int ks = 0; ks < 4; ++ks) {
        int kc = ks * 4 + lk;          // 16B chunk along k (k = kc*8)
        int ar = wid * 16 + lrow;      // A row
        s16x8 a = Xr[(ar << 4) | (kc ^ (ar & 7))];
#pragma unroll
        for (int nt = 0; nt < 8; ++nt) {
            int bc = nt * 16 + lrow;   // B col
            s16x8 b = Wr[(bc << 4) | (kc ^ (bc & 7))];
            acc[nt] = __builtin_amdgcn_mfma_f32_16x16x32_bf16(a, b, acc[nt], 0, 0, 0);
        }
    }
    // epilogue: C/D layout col = l&15, row = (l>>4)*4 + reg
    int rbase = row0 + wid * 16 + lk * 4;
#pragma unroll
    for (int nt = 0; nt < 8; ++nt) {
        int C = nt * 16 + lrow;
        float bv = bias[C] * bscale;
#pragma unroll
        for (int r = 0; r < 4; ++r) {
            int R = rbase + r;
            if (R < N_NODES) {
                float o = fmaxf(acc[nt][r] + bv, 0.f);
                size_t oi = (size_t)R * D + C;
                if (outf) outf[oi] = o;
                if (Hbf) Hbf[oi] = f2bf(o);
                if (Anext) Anext[oi] = f2bf(o * norm[R]);
            }
        }
    }
}

extern "C" void kernel_launch(void* const* d_in, const int* in_sizes, int n_in,
                              void* d_out, int out_size, void* d_ws, size_t ws_size,
                              hipStream_t stream) {
    const float* feat = (const float*)d_in[0];
    const float* W1   = (const float*)d_in[1];
    const float* b1   = (const float*)d_in[2];
    const float* W2   = (const float*)d_in[3];
    const float* b2   = (const float*)d_in[4];
    const int*   src  = (const int*)d_in[5];
    const int*   dst  = (const int*)d_in[6];
    float* out = (float*)d_out;

    char* ws = (char*)d_ws;
    size_t o = 0;
    auto alloc = [&](size_t bytes) {
        void* p = ws + o;
        o += (bytes + 1023) & ~(size_t)1023;
        return p;
    };
    uint_t*   hist  = (uint_t*)alloc((size_t)NCH * N_NODES * 4);   // 25.6 MB
    int*      indeg = (int*)alloc(N_NODES * 4);
    float*    norm  = (float*)alloc(N_NODES * 4);
    float*    rnorm = (float*)alloc(N_NODES * 4);
    int*      off   = (int*)alloc((N_NODES + 1) * 4);
    int*      bsum  = (int*)alloc(NSB * 4);
    int*      bbase = (int*)alloc(NSB * 4);
    int*      csrc  = (int*)alloc((size_t)N_EDGES * 4);
    ushort_t* bufA  = (ushort_t*)alloc((size_t)N_NODES * D * 2);   // A0
    ushort_t* bufB  = (ushort_t*)alloc((size_t)N_NODES * D * 2);   // A1
    ushort_t* bufC  = (ushort_t*)alloc((size_t)N_NODES * D * 2);   // X2
    ushort_t* bufD  = (ushort_t*)alloc((size_t)N_NODES * D * 2);   // H (bf16)
    ushort_t* Wt1   = (ushort_t*)alloc((size_t)D * D * 2);
    ushort_t* Wt2   = (ushort_t*)alloc((size_t)D * D * 2);
    (void)ws_size; (void)in_sizes; (void)n_in; (void)out_size;

    kb_hist<<<dim3(NCH, NR), 256, 0, stream>>>(src, dst, hist);
    kb_reduce<<<(N_NODES + 255) / 256, 256, 0, stream>>>(hist, indeg, norm, rnorm);
    k_scanA<<<NSB, 256, 0, stream>>>(indeg, off, bsum);
    k_scanB<<<1, 256, 0, stream>>>(bsum, bbase, off);
    k_scanC<<<NSB, 256, 0, stream>>>(off, bbase);
    kb_scatter<<<dim3(NCH, NR), 256, 0, stream>>>(src, dst, off, hist, csrc);
    k_prepw<<<(D * D + 255) / 256, 256, 0, stream>>>(W1, Wt1);
    k_prepw<<<(D * D + 255) / 256, 256, 0, stream>>>(W2, Wt2);

    const int init_blocks = (N_NODES * 32 + 255) / 256;
    const int prop_blocks = (N_NODES + 15) / 16;
    const int gemm_blocks = (N_NODES + 63) / 64;

    // ---- layer 1 ----
    k_init<<<init_blocks, 256, 0, stream>>>(feat, norm, bufA);                 // A0
    k_prop<<<prop_blocks, 256, 0, stream>>>(bufA, off, csrc, norm, bufB, 0);   // A1
    k_prop<<<prop_blocks, 256, 0, stream>>>(bufB, off, csrc, norm, bufC, 1);   // X2
    // H = relu((feat + A1*rnorm + X2)W1 + 3b1) -> bf16 bufD; bufA = bf16(H*norm)
    k_gemm_relu<<<gemm_blocks, 256, 0, stream>>>(feat, nullptr, bufB, bufC, rnorm,
                                                 Wt1, b1, nullptr, bufD, bufA, norm, 3.0f);

    // ---- layer 2 ----
    k_prop<<<prop_blocks, 256, 0, stream>>>(bufA, off, csrc, norm, bufB, 0);   // A1
    k_prop<<<prop_blocks, 256, 0, stream>>>(bufB, off, csrc, norm, bufC, 1);   // X2
    k_gemm_relu<<<gemm_blocks, 256, 0, stream>>>(nullptr, bufD, bufB, bufC, rnorm,
                                                 Wt2, b2, out, nullptr, nullptr, norm, 3.0f);
}